// Round 1
// baseline (3511.599 us; speedup 1.0000x reference)
//
#include <hip/hip_runtime.h>
#include <hip/hip_bf16.h>
#include <math.h>

#define D_MODEL 1024
#define SEQ     2048
#define NHEAD   16
#define QB      8      // q-rows per attention block

// ---------------------------------------------------------------------------
// C[M,1024] = A[M,1024] @ W[1024,1024] + bias      (fp32, 64x64 tile, BK=16)
// grid: (N/64, M/64), block: 256 (16x16 threads, 4x4 micro-tile each)
// ---------------------------------------------------------------------------
__global__ __launch_bounds__(256, 4) void gemm_bias_f32(
    const float* __restrict__ A, const float* __restrict__ W,
    const float* __restrict__ bias, float* __restrict__ C) {
  __shared__ float As[16][68];   // [BK][BM] k-major (staged transposed) +pad
  __shared__ float Ws[16][68];   // [BK][BN] +pad
  const int tid = threadIdx.x;
  const int tx = tid & 15, ty = tid >> 4;
  const int row0 = blockIdx.y * 64, col0 = blockIdx.x * 64;
  float acc[4][4] = {};
  for (int k0 = 0; k0 < D_MODEL; k0 += 16) {
    {
      const int r = tid >> 2, c4 = (tid & 3) * 4;   // A: 64 rows x 16 k
      const float4 av = *(const float4*)&A[(size_t)(row0 + r) * D_MODEL + k0 + c4];
      As[c4 + 0][r] = av.x; As[c4 + 1][r] = av.y;
      As[c4 + 2][r] = av.z; As[c4 + 3][r] = av.w;
      const int kr = tid >> 4, j4 = (tid & 15) * 4; // W: 16 k x 64 cols
      *(float4*)&Ws[kr][j4] =
          *(const float4*)&W[(size_t)(k0 + kr) * D_MODEL + col0 + j4];
    }
    __syncthreads();
    #pragma unroll
    for (int kk = 0; kk < 16; ++kk) {
      const float4 a = *(const float4*)&As[kk][ty * 4];
      const float4 w = *(const float4*)&Ws[kk][tx * 4];
      const float av[4] = {a.x, a.y, a.z, a.w};
      const float wv[4] = {w.x, w.y, w.z, w.w};
      #pragma unroll
      for (int i = 0; i < 4; ++i)
        #pragma unroll
        for (int j = 0; j < 4; ++j) acc[i][j] += av[i] * wv[j];
    }
    __syncthreads();
  }
  const float4 bv = *(const float4*)&bias[col0 + tx * 4];
  const float bb[4] = {bv.x, bv.y, bv.z, bv.w};
  #pragma unroll
  for (int i = 0; i < 4; ++i) {
    float4 o;
    o.x = acc[i][0] + bb[0]; o.y = acc[i][1] + bb[1];
    o.z = acc[i][2] + bb[2]; o.w = acc[i][3] + bb[3];
    *(float4*)&C[(size_t)(row0 + ty * 4 + i) * D_MODEL + col0 + tx * 4] = o;
  }
}

// ---------------------------------------------------------------------------
// Attention: one block per (b,h, 8 q-rows). Full logit rows in LDS (64 KB).
//   B: logits = (Q/8)·K^T + mask*NEG_INF   (Q row in VGPRs, K chunk in LDS)
//   C: row softmax (32 lanes/row, shfl reduce), write attn, keep P normalized
//   D: O = P @ V (V chunk staged transposed for float4-over-t reads)
// ---------------------------------------------------------------------------
__global__ __launch_bounds__(256, 2) void attn_f32(
    const float* __restrict__ Q, const float* __restrict__ K,
    const float* __restrict__ V, const int* __restrict__ mask,
    float* __restrict__ attn, float* __restrict__ O) {
  __shared__ float P[QB][SEQ];   // 64 KB logit/prob rows
  __shared__ float Qs[QB][64];   // 2 KB
  __shared__ float KV[2304];     // 9 KB: K chunk [32][68] / V^T chunk [64][36]
  const int tid = threadIdx.x;
  const int bh = blockIdx.y;            // b*16 + h
  const int b = bh >> 4, h = bh & 15;
  const int q0 = blockIdx.x * QB;
  const float* Qp = Q + ((size_t)(b * SEQ + q0)) * D_MODEL + h * 64;
  const float* Kp = K + (size_t)b * SEQ * D_MODEL + h * 64;
  const float* Vp = V + (size_t)b * SEQ * D_MODEL + h * 64;
  const int* mrow = mask + b * SEQ;

  // stage Q tile, pre-scaled by 1/sqrt(64)
  if (tid < 128) {
    const int r = tid >> 4, c4 = (tid & 15) * 4;
    const float4 qv = *(const float4*)&Qp[(size_t)r * D_MODEL + c4];
    Qs[r][c4 + 0] = qv.x * 0.125f; Qs[r][c4 + 1] = qv.y * 0.125f;
    Qs[r][c4 + 2] = qv.z * 0.125f; Qs[r][c4 + 3] = qv.w * 0.125f;
  }
  __syncthreads();

  const int tq = tid >> 5, tt = tid & 31;   // 8 q-rows x 32 t-lanes
  float4 q4[16];
  #pragma unroll
  for (int i = 0; i < 16; ++i) q4[i] = *(const float4*)&Qs[tq][i * 4];

  // ---- phase B: logits
  for (int t0 = 0; t0 < SEQ; t0 += 32) {
    for (int i = tid; i < 512; i += 256) {          // stage K[32][64]
      const int r = i >> 4, c4 = (i & 15) * 4;
      *(float4*)&KV[r * 68 + c4] =
          *(const float4*)&Kp[(size_t)(t0 + r) * D_MODEL + c4];
    }
    __syncthreads();
    const float* krow = &KV[tt * 68];
    float acc = 0.f;
    #pragma unroll
    for (int i = 0; i < 16; ++i) {
      const float4 kv = *(const float4*)&krow[i * 4];
      acc += q4[i].x * kv.x + q4[i].y * kv.y + q4[i].z * kv.z + q4[i].w * kv.w;
    }
    const int t = t0 + tt;
    P[tq][t] = acc + (float)mrow[t] * -1e9f;
    __syncthreads();
  }

  // ---- phase C: softmax + attn write
  {
    float m = -INFINITY;
    #pragma unroll 8
    for (int j = 0; j < 64; ++j) m = fmaxf(m, P[tq][tt + 32 * j]);
    #pragma unroll
    for (int off = 16; off >= 1; off >>= 1) m = fmaxf(m, __shfl_xor(m, off));
    float s = 0.f;
    #pragma unroll 8
    for (int j = 0; j < 64; ++j) {
      const float e = __expf(P[tq][tt + 32 * j] - m);
      P[tq][tt + 32 * j] = e;
      s += e;
    }
    #pragma unroll
    for (int off = 16; off >= 1; off >>= 1) s += __shfl_xor(s, off);
    const float inv = 1.0f / s;
    float* arow = attn + ((size_t)bh * SEQ + (q0 + tq)) * SEQ;
    #pragma unroll 8
    for (int j = 0; j < 64; ++j) {
      const int t = tt + 32 * j;
      const float p = P[tq][t] * inv;
      P[tq][t] = p;
      arow[t] = p;
    }
  }
  __syncthreads();

  // ---- phase D: O = P @ V
  const int d = tid & 63, g = tid >> 6;   // each thread: (q=2g,2g+1, col d)
  float acc0 = 0.f, acc1 = 0.f;
  for (int t0 = 0; t0 < SEQ; t0 += 32) {
    for (int i = tid; i < 512; i += 256) {          // stage V^T: [64 d][32 t]
      const int r = i >> 4, c4 = (i & 15) * 4;
      const float4 vv = *(const float4*)&Vp[(size_t)(t0 + r) * D_MODEL + c4];
      KV[(c4 + 0) * 36 + r] = vv.x;
      KV[(c4 + 1) * 36 + r] = vv.y;
      KV[(c4 + 2) * 36 + r] = vv.z;
      KV[(c4 + 3) * 36 + r] = vv.w;
    }
    __syncthreads();
    const float* vrow = &KV[d * 36];
    const float* p0 = &P[2 * g][t0];
    const float* p1 = &P[2 * g + 1][t0];
    #pragma unroll
    for (int j = 0; j < 8; ++j) {
      const float4 vv = *(const float4*)&vrow[j * 4];
      const float4 pa = *(const float4*)&p0[j * 4];
      const float4 pb = *(const float4*)&p1[j * 4];
      acc0 += pa.x * vv.x + pa.y * vv.y + pa.z * vv.z + pa.w * vv.w;
      acc1 += pb.x * vv.x + pb.y * vv.y + pb.z * vv.z + pb.w * vv.w;
    }
    __syncthreads();
  }
  float* Op = O + ((size_t)(b * SEQ + q0)) * D_MODEL + h * 64;
  Op[(size_t)(2 * g + 0) * D_MODEL + d] = acc0;
  Op[(size_t)(2 * g + 1) * D_MODEL + d] = acc1;
}

// ---------------------------------------------------------------------------
extern "C" void kernel_launch(void* const* d_in, const int* in_sizes, int n_in,
                              void* d_out, int out_size, void* d_ws, size_t ws_size,
                              hipStream_t stream) {
  const float* v    = (const float*)d_in[0];
  const float* k    = (const float*)d_in[1];
  const float* q    = (const float*)d_in[2];
  const int*   mask = (const int*)  d_in[3];
  const float* Wq   = (const float*)d_in[4];
  const float* bq   = (const float*)d_in[5];
  const float* Wk   = (const float*)d_in[6];
  const float* bk   = (const float*)d_in[7];
  const float* Wv   = (const float*)d_in[8];
  const float* bv   = (const float*)d_in[9];
  const float* Wo   = (const float*)d_in[10];
  const float* bo   = (const float*)d_in[11];

  const size_t NTOK = (size_t)2 * SEQ;           // 4096 rows
  const size_t TOKF = NTOK * D_MODEL;            // 4,194,304 floats
  float* out  = (float*)d_out;
  float* attn = out + TOKF;                      // output 1 region
  // workspace: Q,K,V,O buffers (4 x 16 MiB = 64 MiB required of d_ws)
  float* Qb = (float*)d_ws;
  float* Kb = Qb + TOKF;
  float* Vb = Kb + TOKF;
  float* Ob = Vb + TOKF;

  const dim3 gg(D_MODEL / 64, NTOK / 64);        // (16, 64)
  gemm_bias_f32<<<gg, 256, 0, stream>>>(q, Wq, bq, Qb);
  gemm_bias_f32<<<gg, 256, 0, stream>>>(k, Wk, bk, Kb);
  gemm_bias_f32<<<gg, 256, 0, stream>>>(v, Wv, bv, Vb);
  attn_f32<<<dim3(SEQ / QB, 2 * NHEAD), 256, 0, stream>>>(Qb, Kb, Vb, mask, attn, Ob);
  gemm_bias_f32<<<gg, 256, 0, stream>>>(Ob, Wo, bo, out);
}

// Round 2
// 799.987 us; speedup vs baseline: 4.3896x; 4.3896x over previous
//
#include <hip/hip_runtime.h>
#include <hip/hip_bf16.h>
#include <math.h>

#define D_MODEL 1024
#define SEQ     2048
#define NHEAD   16

typedef __attribute__((ext_vector_type(8))) short bf16x8;
typedef __attribute__((ext_vector_type(4))) float f32x4;
typedef const __attribute__((address_space(1))) unsigned int* gas_u32p;
typedef __attribute__((address_space(3))) unsigned int* las_u32p;

__device__ __forceinline__ void load16(const void* g, void* l) {
  __builtin_amdgcn_global_load_lds((gas_u32p)g, (las_u32p)l, 16, 0, 0);
}

__device__ __forceinline__ unsigned short f2bf(float f) {
  __hip_bfloat16 h = __float2bfloat16(f);
  return *(unsigned short*)&h;
}

// ---------------------------------------------------------------------------
// fp32 GEMM (used for final out = Ob @ Wo + bo). 64x64 tile, BK=16.
// ---------------------------------------------------------------------------
__global__ __launch_bounds__(256, 4) void gemm_bias_f32(
    const float* __restrict__ A, const float* __restrict__ W,
    const float* __restrict__ bias, float* __restrict__ C) {
  __shared__ float As[16][68];
  __shared__ float Ws[16][68];
  const int tid = threadIdx.x;
  const int tx = tid & 15, ty = tid >> 4;
  const int row0 = blockIdx.y * 64, col0 = blockIdx.x * 64;
  float acc[4][4] = {};
  for (int k0 = 0; k0 < D_MODEL; k0 += 16) {
    {
      const int r = tid >> 2, c4 = (tid & 3) * 4;
      const float4 av = *(const float4*)&A[(size_t)(row0 + r) * D_MODEL + k0 + c4];
      As[c4 + 0][r] = av.x; As[c4 + 1][r] = av.y;
      As[c4 + 2][r] = av.z; As[c4 + 3][r] = av.w;
      const int kr = tid >> 4, j4 = (tid & 15) * 4;
      *(float4*)&Ws[kr][j4] =
          *(const float4*)&W[(size_t)(k0 + kr) * D_MODEL + col0 + j4];
    }
    __syncthreads();
    #pragma unroll
    for (int kk = 0; kk < 16; ++kk) {
      const float4 a = *(const float4*)&As[kk][ty * 4];
      const float4 w = *(const float4*)&Ws[kk][tx * 4];
      const float av[4] = {a.x, a.y, a.z, a.w};
      const float wv[4] = {w.x, w.y, w.z, w.w};
      #pragma unroll
      for (int i = 0; i < 4; ++i)
        #pragma unroll
        for (int j = 0; j < 4; ++j) acc[i][j] += av[i] * wv[j];
    }
    __syncthreads();
  }
  const float4 bv = *(const float4*)&bias[col0 + tx * 4];
  const float bb[4] = {bv.x, bv.y, bv.z, bv.w};
  #pragma unroll
  for (int i = 0; i < 4; ++i) {
    float4 o;
    o.x = acc[i][0] + bb[0]; o.y = acc[i][1] + bb[1];
    o.z = acc[i][2] + bb[2]; o.w = acc[i][3] + bb[3];
    *(float4*)&C[(size_t)(row0 + ty * 4 + i) * D_MODEL + col0 + tx * 4] = o;
  }
}

// ---------------------------------------------------------------------------
// fp32 GEMM, bf16 row-major output with scale (Q: scale=0.125, K: scale=1)
// ---------------------------------------------------------------------------
__global__ __launch_bounds__(256, 4) void gemm_bias_bf16(
    const float* __restrict__ A, const float* __restrict__ W,
    const float* __restrict__ bias, unsigned short* __restrict__ C, float scale) {
  __shared__ float As[16][68];
  __shared__ float Ws[16][68];
  const int tid = threadIdx.x;
  const int tx = tid & 15, ty = tid >> 4;
  const int row0 = blockIdx.y * 64, col0 = blockIdx.x * 64;
  float acc[4][4] = {};
  for (int k0 = 0; k0 < D_MODEL; k0 += 16) {
    {
      const int r = tid >> 2, c4 = (tid & 3) * 4;
      const float4 av = *(const float4*)&A[(size_t)(row0 + r) * D_MODEL + k0 + c4];
      As[c4 + 0][r] = av.x; As[c4 + 1][r] = av.y;
      As[c4 + 2][r] = av.z; As[c4 + 3][r] = av.w;
      const int kr = tid >> 4, j4 = (tid & 15) * 4;
      *(float4*)&Ws[kr][j4] =
          *(const float4*)&W[(size_t)(k0 + kr) * D_MODEL + col0 + j4];
    }
    __syncthreads();
    #pragma unroll
    for (int kk = 0; kk < 16; ++kk) {
      const float4 a = *(const float4*)&As[kk][ty * 4];
      const float4 w = *(const float4*)&Ws[kk][tx * 4];
      const float av[4] = {a.x, a.y, a.z, a.w};
      const float wv[4] = {w.x, w.y, w.z, w.w};
      #pragma unroll
      for (int i = 0; i < 4; ++i)
        #pragma unroll
        for (int j = 0; j < 4; ++j) acc[i][j] += av[i] * wv[j];
    }
    __syncthreads();
  }
  const float4 bv = *(const float4*)&bias[col0 + tx * 4];
  const float bb[4] = {bv.x, bv.y, bv.z, bv.w};
  #pragma unroll
  for (int i = 0; i < 4; ++i) {
    ushort4 u;
    u.x = f2bf((acc[i][0] + bb[0]) * scale);
    u.y = f2bf((acc[i][1] + bb[1]) * scale);
    u.z = f2bf((acc[i][2] + bb[2]) * scale);
    u.w = f2bf((acc[i][3] + bb[3]) * scale);
    *(ushort4*)&C[(size_t)(row0 + ty * 4 + i) * D_MODEL + col0 + tx * 4] = u;
  }
}

// ---------------------------------------------------------------------------
// fp32 GEMM, bf16 output written TRANSPOSED per head: Vt[(b*16+h)*64+d][t]
// ---------------------------------------------------------------------------
__global__ __launch_bounds__(256, 4) void gemm_bias_bf16_vt(
    const float* __restrict__ A, const float* __restrict__ W,
    const float* __restrict__ bias, unsigned short* __restrict__ VtOut) {
  __shared__ float As[16][68];
  __shared__ float Ws[16][68];
  const int tid = threadIdx.x;
  const int tx = tid & 15, ty = tid >> 4;
  const int row0 = blockIdx.y * 64, col0 = blockIdx.x * 64;
  float acc[4][4] = {};
  for (int k0 = 0; k0 < D_MODEL; k0 += 16) {
    {
      const int r = tid >> 2, c4 = (tid & 3) * 4;
      const float4 av = *(const float4*)&A[(size_t)(row0 + r) * D_MODEL + k0 + c4];
      As[c4 + 0][r] = av.x; As[c4 + 1][r] = av.y;
      As[c4 + 2][r] = av.z; As[c4 + 3][r] = av.w;
      const int kr = tid >> 4, j4 = (tid & 15) * 4;
      *(float4*)&Ws[kr][j4] =
          *(const float4*)&W[(size_t)(k0 + kr) * D_MODEL + col0 + j4];
    }
    __syncthreads();
    #pragma unroll
    for (int kk = 0; kk < 16; ++kk) {
      const float4 a = *(const float4*)&As[kk][ty * 4];
      const float4 w = *(const float4*)&Ws[kk][tx * 4];
      const float av[4] = {a.x, a.y, a.z, a.w};
      const float wv[4] = {w.x, w.y, w.z, w.w};
      #pragma unroll
      for (int i = 0; i < 4; ++i)
        #pragma unroll
        for (int j = 0; j < 4; ++j) acc[i][j] += av[i] * wv[j];
    }
    __syncthreads();
  }
  const float4 bv = *(const float4*)&bias[col0 + tx * 4];
  const float bb[4] = {bv.x, bv.y, bv.z, bv.w};
  const int r = row0 + ty * 4;            // token base (4 consecutive tokens)
  const int b_ = r >> 11, tt = r & 2047;
  #pragma unroll
  for (int j = 0; j < 4; ++j) {
    const int col = col0 + tx * 4 + j;    // d_model column
    const int hh = col >> 6, dd = col & 63;
    ushort4 u;
    u.x = f2bf(acc[0][j] + bb[j]);
    u.y = f2bf(acc[1][j] + bb[j]);
    u.z = f2bf(acc[2][j] + bb[j]);
    u.w = f2bf(acc[3][j] + bb[j]);
    *(ushort4*)&VtOut[((size_t)(b_ * NHEAD + hh) * 64 + dd) * SEQ + tt] = u;
  }
}

// ---------------------------------------------------------------------------
// MFMA attention. Block = (b,h, 32 q-rows), 512 threads (8 waves).
// LDS map (163840 B total):
//   [0,131072)       P[32 q][2048 t] bf16, byte=(q*4096+t*2) ^ (((q>>2)&3)<<5)
//   [131072,147456)  K dbuf 2x[64 t][64 d] bf16 (linear; src pre-swizzled)
//                    (overlaid: Q staging at start, rowsum red[8][16] at end)
//   [147456,163840)  Vt dbuf 2x[64 d][64 t] bf16
// Fragment reads XOR byte ^ ((row&7)<<4) to match pre-swizzled staging.
// Waves: qh=wid>>2 (q half), wt=wid&3 (t window for S / d window for PV).
// No max-subtraction: logits bounded (~|8|), masked lanes exact 0.
// ---------------------------------------------------------------------------
__global__ __launch_bounds__(512, 1) void attn_mfma(
    const unsigned short* __restrict__ Qb,   // bf16 [4096][1024], pre-scaled /8
    const unsigned short* __restrict__ Kb,   // bf16 [4096][1024]
    const unsigned short* __restrict__ Vt,   // bf16 [32*64][2048]
    const int* __restrict__ mask,            // [2][2048]
    float* __restrict__ attn,                // [32][2048][2048]
    float* __restrict__ Ob) {                // [4096][1024] fp32
  __shared__ char lds[163840];
  char* const Pb  = lds;
  char* const KB_ = lds + 131072;
  char* const VB_ = lds + 147456;

  const int tid  = threadIdx.x;
  const int lane = tid & 63;
  const int wid  = tid >> 6;
  const int r16  = lane & 15;
  const int g    = lane >> 4;

  // XCD-aware swizzle (2048 % 8 == 0 -> simple bijection); 4 heads per XCD.
  const int bid  = blockIdx.x;
  const int orig = (bid & 7) * 256 + (bid >> 3);
  const int bh   = orig >> 6;
  const int qblk = orig & 63;
  const int b    = bh >> 4, h = bh & 15;
  const int q0   = qblk * 32;

  const unsigned short* Kg0 = Kb + (size_t)(b * SEQ) * D_MODEL + h * 64;
  const unsigned short* Qg0 = Qb + (size_t)(b * SEQ + q0) * D_MODEL + h * 64;
  const unsigned short* Vg0 = Vt + (size_t)(bh * 64) * SEQ;
  const int* mrow = mask + b * SEQ;

  const int srow = tid >> 3, sch = tid & 7;   // staging: row, 16B-chunk
  const int ssw  = (srow & 7);                // source chunk swizzle

  // ---- prologue: V(0) + Q staged; Q A-frags to registers -----------------
  {
    const char* vsrc = (const char*)(Vg0 + (size_t)srow * SEQ) + ((sch ^ ssw) << 4);
    load16(vsrc, VB_ + (wid << 10));
  }
  if (tid < 256) {
    const char* qsrc = (const char*)(Qg0 + (size_t)srow * D_MODEL) + ((sch ^ ssw) << 4);
    load16(qsrc, KB_ + (wid << 10));
  }
  __syncthreads();
  const int qh = wid >> 2;
  const int wt = wid & 3;
  bf16x8 qa0, qa1;
  {
    const int row = qh * 16 + r16;
    const int sw = (row & 7) << 4;
    qa0 = *(const bf16x8*)(KB_ + row * 128 + ((g * 16) ^ sw));
    qa1 = *(const bf16x8*)(KB_ + row * 128 + ((g * 16 + 64) ^ sw));
  }
  __syncthreads();
  {  // K(0) into KB buffer 0
    const char* ksrc = (const char*)(Kg0 + (size_t)srow * D_MODEL) + ((sch ^ ssw) << 4);
    load16(ksrc, KB_ + (wid << 10));
  }

  // ---- main loop ---------------------------------------------------------
  float rs0 = 0.f, rs1 = 0.f, rs2 = 0.f, rs3 = 0.f;
  f32x4 oacc = {0.f, 0.f, 0.f, 0.f};
  const int krow = wt * 16 + r16;         // K-tile row (t) / Vt row (d)
  const int ksw  = (krow & 7) << 4;

  for (int i = 0; i < 32; ++i) {
    __syncthreads();   // tiles i resident (drains vmcnt); prev compute done
    if (i < 31) {
      const int nb = (i + 1) & 1;
      const char* ksrc = (const char*)(Kg0 + (size_t)((i + 1) * 64 + srow) * D_MODEL)
                         + ((sch ^ ssw) << 4);
      load16(ksrc, KB_ + (nb << 13) + (wid << 10));
      const char* vsrc = (const char*)(Vg0 + (size_t)srow * SEQ + (i + 1) * 64)
                         + ((sch ^ ssw) << 4);
      load16(vsrc, VB_ + (nb << 13) + (wid << 10));
    }
    char* const Kt  = KB_ + ((i & 1) << 13);
    char* const Vtl = VB_ + ((i & 1) << 13);

    // ---- S = Q K^T (this wave: 16 q x 16 t), exp, P write, rowsum
    const bf16x8 kb0 = *(const bf16x8*)(Kt + krow * 128 + ((g * 16) ^ ksw));
    const bf16x8 kb1 = *(const bf16x8*)(Kt + krow * 128 + ((g * 16 + 64) ^ ksw));
    f32x4 c = {0.f, 0.f, 0.f, 0.f};
    c = __builtin_amdgcn_mfma_f32_16x16x32_bf16(qa0, kb0, c, 0, 0, 0);
    c = __builtin_amdgcn_mfma_f32_16x16x32_bf16(qa1, kb1, c, 0, 0, 0);

    const int tg = i * 64 + wt * 16 + r16;          // block-local t
    const int mk = mrow[tg];
    {
      const int qb_ = qh * 16 + g * 4;              // row base (mult of 4)
      const int psw = ((qb_ >> 2) & 3) << 5;
      const int pb  = qb_ * 4096 + tg * 2;
      const float e0 = mk ? 0.f : __expf(c[0]);
      const float e1 = mk ? 0.f : __expf(c[1]);
      const float e2 = mk ? 0.f : __expf(c[2]);
      const float e3 = mk ? 0.f : __expf(c[3]);
      rs0 += e0; rs1 += e1; rs2 += e2; rs3 += e3;
      *(unsigned short*)(Pb + ((pb + 0 * 4096) ^ psw)) = f2bf(e0);
      *(unsigned short*)(Pb + ((pb + 1 * 4096) ^ psw)) = f2bf(e1);
      *(unsigned short*)(Pb + ((pb + 2 * 4096) ^ psw)) = f2bf(e2);
      *(unsigned short*)(Pb + ((pb + 3 * 4096) ^ psw)) = f2bf(e3);
    }

    // P visible to peer waves; do NOT drain vmcnt (prefetch stays in flight)
    asm volatile("s_waitcnt lgkmcnt(0)\n\ts_barrier" ::: "memory");

    // ---- O += P V (this wave: 16 q (qh) x 16 d (wt window))
    {
      const int prow = qh * 16 + r16;
      const int psw  = ((prow >> 2) & 3) << 5;
      const int pbse = prow * 4096 + i * 128 + g * 16;
      const bf16x8 pa0 = *(const bf16x8*)(Pb + (pbse ^ psw));
      const bf16x8 pa1 = *(const bf16x8*)(Pb + ((pbse + 64) ^ psw));
      const bf16x8 vb0 = *(const bf16x8*)(Vtl + krow * 128 + ((g * 16) ^ ksw));
      const bf16x8 vb1 = *(const bf16x8*)(Vtl + krow * 128 + ((g * 16 + 64) ^ ksw));
      oacc = __builtin_amdgcn_mfma_f32_16x16x32_bf16(pa0, vb0, oacc, 0, 0, 0);
      oacc = __builtin_amdgcn_mfma_f32_16x16x32_bf16(pa1, vb1, oacc, 0, 0, 0);
    }
  }

  // ---- epilogue ----------------------------------------------------------
  __syncthreads();
  float* red = (float*)KB_;   // [8 waves][16 q-tile]
  rs0 += __shfl_xor(rs0, 1); rs0 += __shfl_xor(rs0, 2);
  rs0 += __shfl_xor(rs0, 4); rs0 += __shfl_xor(rs0, 8);
  rs1 += __shfl_xor(rs1, 1); rs1 += __shfl_xor(rs1, 2);
  rs1 += __shfl_xor(rs1, 4); rs1 += __shfl_xor(rs1, 8);
  rs2 += __shfl_xor(rs2, 1); rs2 += __shfl_xor(rs2, 2);
  rs2 += __shfl_xor(rs2, 4); rs2 += __shfl_xor(rs2, 8);
  rs3 += __shfl_xor(rs3, 1); rs3 += __shfl_xor(rs3, 2);
  rs3 += __shfl_xor(rs3, 4); rs3 += __shfl_xor(rs3, 8);
  if (r16 == 0) {
    red[wid * 16 + g * 4 + 0] = rs0;
    red[wid * 16 + g * 4 + 1] = rs1;
    red[wid * 16 + g * 4 + 2] = rs2;
    red[wid * 16 + g * 4 + 3] = rs3;
  }
  __syncthreads();

  {  // O write (normalized)
    #pragma unroll
    for (int rr = 0; rr < 4; ++rr) {
      const int qt = g * 4 + rr;
      const float l = red[(qh * 4 + 0) * 16 + qt] + red[(qh * 4 + 1) * 16 + qt]
                    + red[(qh * 4 + 2) * 16 + qt] + red[(qh * 4 + 3) * 16 + qt];
      Ob[(size_t)(b * SEQ + q0 + qh * 16 + qt) * D_MODEL + h * 64 + wt * 16 + r16] =
          oacc[rr] / l;
    }
  }

  {  // attn write (normalized fp32, coalesced float4)
    #pragma unroll
    for (int rq = 0; rq < 4; ++rq) {
      const int q  = wid * 4 + rq;
      const int qt = q & 15, qh2 = q >> 4;
      const float l = red[(qh2 * 4 + 0) * 16 + qt] + red[(qh2 * 4 + 1) * 16 + qt]
                    + red[(qh2 * 4 + 2) * 16 + qt] + red[(qh2 * 4 + 3) * 16 + qt];
      const float inv = 1.f / l;
      const int psw = ((q >> 2) & 3) << 5;
      const char* prow = Pb + q * 4096;
      float* arow = attn + ((size_t)bh * SEQ + q0 + q) * SEQ;
      #pragma unroll
      for (int ch = 0; ch < 8; ++ch) {
        const int off = (ch * 512 + lane * 8) ^ psw;
        const ushort4 pv4 = *(const ushort4*)(prow + off);
        float4 o;
        o.x = __uint_as_float((unsigned)pv4.x << 16) * inv;
        o.y = __uint_as_float((unsigned)pv4.y << 16) * inv;
        o.z = __uint_as_float((unsigned)pv4.z << 16) * inv;
        o.w = __uint_as_float((unsigned)pv4.w << 16) * inv;
        *(float4*)&arow[ch * 256 + lane * 4] = o;
      }
    }
  }
}

// ---------------------------------------------------------------------------
extern "C" void kernel_launch(void* const* d_in, const int* in_sizes, int n_in,
                              void* d_out, int out_size, void* d_ws, size_t ws_size,
                              hipStream_t stream) {
  const float* v    = (const float*)d_in[0];
  const float* k    = (const float*)d_in[1];
  const float* q    = (const float*)d_in[2];
  const int*   mask = (const int*)  d_in[3];
  const float* Wq   = (const float*)d_in[4];
  const float* bq   = (const float*)d_in[5];
  const float* Wk   = (const float*)d_in[6];
  const float* bk   = (const float*)d_in[7];
  const float* Wv   = (const float*)d_in[8];
  const float* bv   = (const float*)d_in[9];
  const float* Wo   = (const float*)d_in[10];
  const float* bo   = (const float*)d_in[11];

  const size_t NTOK = (size_t)2 * SEQ;            // 4096 tokens
  const size_t TOKF = NTOK * D_MODEL;             // 4,194,304 elements
  float* out  = (float*)d_out;
  float* attn = out + TOKF;

  unsigned short* Qbf = (unsigned short*)d_ws;    // 8 MB bf16
  unsigned short* Kbf = Qbf + TOKF;               // 8 MB
  unsigned short* Vtb = Kbf + TOKF;               // 8 MB (transposed per head)
  float*          Obf = (float*)(Vtb + TOKF);     // 16 MB fp32

  const dim3 gg(D_MODEL / 64, NTOK / 64);         // (16, 64)
  gemm_bias_bf16  <<<gg, 256, 0, stream>>>(q, Wq, bq, Qbf, 0.125f);
  gemm_bias_bf16  <<<gg, 256, 0, stream>>>(k, Wk, bk, Kbf, 1.0f);
  gemm_bias_bf16_vt<<<gg, 256, 0, stream>>>(v, Wv, bv, Vtb);
  attn_mfma<<<2048, 512, 0, stream>>>(Qbf, Kbf, Vtb, mask, attn, Obf);
  gemm_bias_f32   <<<gg, 256, 0, stream>>>(Obf, Wo, bo, out);
}

// Round 3
// 404.600 us; speedup vs baseline: 8.6792x; 1.9772x over previous
//
#include <hip/hip_runtime.h>
#include <hip/hip_bf16.h>
#include <math.h>

#define D_MODEL 1024
#define SEQ     2048
#define NHEAD   16

typedef __attribute__((ext_vector_type(8))) short bf16x8;
typedef __attribute__((ext_vector_type(4))) float f32x4;
typedef const __attribute__((address_space(1))) unsigned int* gas_u32p;
typedef __attribute__((address_space(3))) unsigned int* las_u32p;

__device__ __forceinline__ void load16(const void* g, void* l) {
  __builtin_amdgcn_global_load_lds((gas_u32p)g, (las_u32p)l, 16, 0, 0);
}

__device__ __forceinline__ unsigned short f2bf(float f) {
  __hip_bfloat16 h = __float2bfloat16(f);
  return *(unsigned short*)&h;
}
__device__ __forceinline__ float bf2f(unsigned short u) {
  return __uint_as_float((unsigned)u << 16);
}

// ---------------------------------------------------------------------------
// fp32 -> bf16 elementwise (float4 -> ushort4), n/4 work items
// ---------------------------------------------------------------------------
__global__ __launch_bounds__(256) void cvt_bf16(
    const float4* __restrict__ in, ushort4* __restrict__ out) {
  const int i = blockIdx.x * 256 + threadIdx.x;
  const float4 f = in[i];
  ushort4 u;
  u.x = f2bf(f.x); u.y = f2bf(f.y); u.z = f2bf(f.z); u.w = f2bf(f.w);
  out[i] = u;
}

// ---------------------------------------------------------------------------
// W [1024 k][1024 n] fp32 -> Wt bf16 [n][k] (hi, and optionally lo part)
// ---------------------------------------------------------------------------
template <bool LO>
__global__ __launch_bounds__(256) void wt_cvt(
    const float* __restrict__ W, unsigned short* __restrict__ Wh,
    unsigned short* __restrict__ Wl) {
  __shared__ float t[64][65];
  const int tid = threadIdx.x;
  const int k0 = blockIdx.y * 64, n0 = blockIdx.x * 64;
  #pragma unroll
  for (int it = 0; it < 4; ++it) {
    const int r = it * 16 + (tid >> 4), c4 = (tid & 15) * 4;
    const float4 f = *(const float4*)&W[(size_t)(k0 + r) * D_MODEL + n0 + c4];
    t[r][c4 + 0] = f.x; t[r][c4 + 1] = f.y;
    t[r][c4 + 2] = f.z; t[r][c4 + 3] = f.w;
  }
  __syncthreads();
  #pragma unroll
  for (int it = 0; it < 4; ++it) {
    const int n = it * 16 + (tid >> 4), k4 = (tid & 15) * 4;
    float fs[4];
    fs[0] = t[k4 + 0][n]; fs[1] = t[k4 + 1][n];
    fs[2] = t[k4 + 2][n]; fs[3] = t[k4 + 3][n];
    ushort4 uh;
    uh.x = f2bf(fs[0]); uh.y = f2bf(fs[1]);
    uh.z = f2bf(fs[2]); uh.w = f2bf(fs[3]);
    *(ushort4*)&Wh[(size_t)(n0 + n) * D_MODEL + k0 + k4] = uh;
    if (LO) {
      ushort4 ul;
      ul.x = f2bf(fs[0] - bf2f(uh.x)); ul.y = f2bf(fs[1] - bf2f(uh.y));
      ul.z = f2bf(fs[2] - bf2f(uh.z)); ul.w = f2bf(fs[3] - bf2f(uh.w));
      *(ushort4*)&Wl[(size_t)(n0 + n) * D_MODEL + k0 + k4] = ul;
    }
  }
}

// ---------------------------------------------------------------------------
// bf16 MFMA GEMM, 64x64 tile, BK=64, 256 threads (4 waves, 2x2), 1024 blocks.
// A [4096][1024] bf16 row-major; B = Wt [1024 n][1024 k] bf16 (transposed).
// MODE 0: Cout bf16 = bf16((A*Wt + bias) * scale)
// MODE 1: Cout = Vt bf16 [(b*16+h)*64+d][t]  (per-head transposed V)
// MODE 2: Cout fp32 = A*Bh + A*Bl + Al*Bh + bias   (split-precision final)
// Staging: global_load_lds w16, linear LDS dest, pre-swizzled source chunks.
// ---------------------------------------------------------------------------
template <int MODE>
__global__ __launch_bounds__(256, 2) void gemm64(
    const unsigned short* __restrict__ A, const unsigned short* __restrict__ Al,
    const unsigned short* __restrict__ Bh, const unsigned short* __restrict__ Bl,
    const float* __restrict__ bias, void* __restrict__ outp, float scale) {
  constexpr int NT = (MODE == 2) ? 4 : 2;      // tiles per buffer (8KB each)
  __shared__ char lds[NT * 8192 * 2];
  const int tid = threadIdx.x;
  const int lane = tid & 63, wid = tid >> 6;
  const int r16 = lane & 15, g = lane >> 4;
  const int bid = blockIdx.x;
  const int orig = (bid & 7) * 128 + (bid >> 3);   // XCD swizzle (1024%8==0)
  const int bm = orig >> 4, bn = orig & 15;
  const int row0 = bm * 64, col0 = bn * 64;
  const int wm = wid >> 1, wn = wid & 1;

  const int srow = tid >> 3, sch = tid & 7;

  const unsigned short* Ag  = A + (size_t)row0 * D_MODEL;
  const unsigned short* Bg  = Bh + (size_t)col0 * D_MODEL;
  const unsigned short* Alg = (MODE == 2) ? Al + (size_t)row0 * D_MODEL : nullptr;
  const unsigned short* Blg = (MODE == 2) ? Bl + (size_t)col0 * D_MODEL : nullptr;

  auto stage_tile = [&](const unsigned short* g0, char* dst, int k0) {
    #pragma unroll
    for (int c = 0; c < 2; ++c) {
      const int r = c * 32 + srow;
      const unsigned short* src =
          g0 + (size_t)r * D_MODEL + k0 + ((sch ^ (r & 7)) << 3);
      load16(src, dst + c * 4096 + tid * 16);
    }
  };
  auto stage = [&](int buf, int k0) {
    char* base = lds + buf * (NT * 8192);
    stage_tile(Ag, base, k0);
    stage_tile(Bg, base + 8192, k0);
    if constexpr (MODE == 2) {
      stage_tile(Alg, base + 16384, k0);
      stage_tile(Blg, base + 24576, k0);
    }
  };

  stage(0, 0);
  f32x4 acc[2][2] = {};

  for (int s = 0; s < 16; ++s) {
    __syncthreads();                 // tile s resident (drains vmcnt)
    if (s < 15) stage((s + 1) & 1, (s + 1) * 64);
    const char* base = lds + (s & 1) * (NT * 8192);
    #pragma unroll
    for (int kk = 0; kk < 2; ++kk) {
      bf16x8 a[2], b[2];
      #pragma unroll
      for (int mi = 0; mi < 2; ++mi) {
        const int r = wm * 32 + mi * 16 + r16;
        a[mi] = *(const bf16x8*)(base + r * 128 + (((g + kk * 4) ^ (r & 7)) << 4));
      }
      #pragma unroll
      for (int ni = 0; ni < 2; ++ni) {
        const int r = wn * 32 + ni * 16 + r16;
        b[ni] = *(const bf16x8*)(base + 8192 + r * 128 +
                                 (((g + kk * 4) ^ (r & 7)) << 4));
      }
      #pragma unroll
      for (int mi = 0; mi < 2; ++mi)
        #pragma unroll
        for (int ni = 0; ni < 2; ++ni)
          acc[mi][ni] = __builtin_amdgcn_mfma_f32_16x16x32_bf16(
              a[mi], b[ni], acc[mi][ni], 0, 0, 0);
      if constexpr (MODE == 2) {
        bf16x8 al[2], bl[2];
        #pragma unroll
        for (int mi = 0; mi < 2; ++mi) {
          const int r = wm * 32 + mi * 16 + r16;
          al[mi] = *(const bf16x8*)(base + 16384 + r * 128 +
                                    (((g + kk * 4) ^ (r & 7)) << 4));
        }
        #pragma unroll
        for (int ni = 0; ni < 2; ++ni) {
          const int r = wn * 32 + ni * 16 + r16;
          bl[ni] = *(const bf16x8*)(base + 24576 + r * 128 +
                                    (((g + kk * 4) ^ (r & 7)) << 4));
        }
        #pragma unroll
        for (int mi = 0; mi < 2; ++mi)
          #pragma unroll
          for (int ni = 0; ni < 2; ++ni) {
            acc[mi][ni] = __builtin_amdgcn_mfma_f32_16x16x32_bf16(
                a[mi], bl[ni], acc[mi][ni], 0, 0, 0);
            acc[mi][ni] = __builtin_amdgcn_mfma_f32_16x16x32_bf16(
                al[mi], b[ni], acc[mi][ni], 0, 0, 0);
          }
      }
    }
  }

  // ---- epilogue ----------------------------------------------------------
  if constexpr (MODE == 0) {
    unsigned short* C = (unsigned short*)outp;
    #pragma unroll
    for (int mi = 0; mi < 2; ++mi)
      #pragma unroll
      for (int ni = 0; ni < 2; ++ni) {
        const int col = col0 + wn * 32 + ni * 16 + r16;
        const float bb = bias[col];
        const int rowb = row0 + wm * 32 + mi * 16 + g * 4;
        #pragma unroll
        for (int j = 0; j < 4; ++j)
          C[(size_t)(rowb + j) * D_MODEL + col] =
              f2bf((acc[mi][ni][j] + bb) * scale);
      }
  } else if constexpr (MODE == 1) {
    unsigned short* Vt = (unsigned short*)outp;
    #pragma unroll
    for (int mi = 0; mi < 2; ++mi)
      #pragma unroll
      for (int ni = 0; ni < 2; ++ni) {
        const int col = col0 + wn * 32 + ni * 16 + r16;
        const int hh = col >> 6, dd = col & 63;
        const float bb = bias[col];
        const int rowb = row0 + wm * 32 + mi * 16 + g * 4;
        const int b_ = rowb >> 11, tt = rowb & 2047;
        ushort4 u;
        u.x = f2bf(acc[mi][ni][0] + bb);
        u.y = f2bf(acc[mi][ni][1] + bb);
        u.z = f2bf(acc[mi][ni][2] + bb);
        u.w = f2bf(acc[mi][ni][3] + bb);
        *(ushort4*)&Vt[((size_t)((b_ * NHEAD + hh) * 64 + dd)) * SEQ + tt] = u;
      }
  } else {
    float* O = (float*)outp;
    #pragma unroll
    for (int mi = 0; mi < 2; ++mi)
      #pragma unroll
      for (int ni = 0; ni < 2; ++ni) {
        const int col = col0 + wn * 32 + ni * 16 + r16;
        const float bb = bias[col];
        const int rowb = row0 + wm * 32 + mi * 16 + g * 4;
        #pragma unroll
        for (int j = 0; j < 4; ++j)
          O[(size_t)(rowb + j) * D_MODEL + col] = acc[mi][ni][j] + bb;
      }
  }
}

// ---------------------------------------------------------------------------
// MFMA attention (validated round 2). Block = (b,h, 32 q-rows), 512 threads.
// Epilogue now emits O as bf16 hi+lo pair for the split final GEMM.
// ---------------------------------------------------------------------------
__global__ __launch_bounds__(512, 1) void attn_mfma(
    const unsigned short* __restrict__ Qb,   // bf16 [4096][1024], pre-scaled /8
    const unsigned short* __restrict__ Kb,   // bf16 [4096][1024]
    const unsigned short* __restrict__ Vt,   // bf16 [32*64][2048]
    const int* __restrict__ mask,            // [2][2048]
    float* __restrict__ attn,                // [32][2048][2048]
    unsigned short* __restrict__ Oh,         // bf16 hi [4096][1024]
    unsigned short* __restrict__ Ol) {       // bf16 lo [4096][1024]
  __shared__ char lds[163840];
  char* const Pb  = lds;
  char* const KB_ = lds + 131072;
  char* const VB_ = lds + 147456;

  const int tid  = threadIdx.x;
  const int lane = tid & 63;
  const int wid  = tid >> 6;
  const int r16  = lane & 15;
  const int g    = lane >> 4;

  const int bid  = blockIdx.x;
  const int orig = (bid & 7) * 256 + (bid >> 3);
  const int bh   = orig >> 6;
  const int qblk = orig & 63;
  const int b    = bh >> 4, h = bh & 15;
  const int q0   = qblk * 32;

  const unsigned short* Kg0 = Kb + (size_t)(b * SEQ) * D_MODEL + h * 64;
  const unsigned short* Qg0 = Qb + (size_t)(b * SEQ + q0) * D_MODEL + h * 64;
  const unsigned short* Vg0 = Vt + (size_t)(bh * 64) * SEQ;
  const int* mrow = mask + b * SEQ;

  const int srow = tid >> 3, sch = tid & 7;
  const int ssw  = (srow & 7);

  {
    const char* vsrc = (const char*)(Vg0 + (size_t)srow * SEQ) + ((sch ^ ssw) << 4);
    load16(vsrc, VB_ + (wid << 10));
  }
  if (tid < 256) {
    const char* qsrc = (const char*)(Qg0 + (size_t)srow * D_MODEL) + ((sch ^ ssw) << 4);
    load16(qsrc, KB_ + (wid << 10));
  }
  __syncthreads();
  const int qh = wid >> 2;
  const int wt = wid & 3;
  bf16x8 qa0, qa1;
  {
    const int row = qh * 16 + r16;
    const int sw = (row & 7) << 4;
    qa0 = *(const bf16x8*)(KB_ + row * 128 + ((g * 16) ^ sw));
    qa1 = *(const bf16x8*)(KB_ + row * 128 + ((g * 16 + 64) ^ sw));
  }
  __syncthreads();
  {
    const char* ksrc = (const char*)(Kg0 + (size_t)srow * D_MODEL) + ((sch ^ ssw) << 4);
    load16(ksrc, KB_ + (wid << 10));
  }

  float rs0 = 0.f, rs1 = 0.f, rs2 = 0.f, rs3 = 0.f;
  f32x4 oacc = {0.f, 0.f, 0.f, 0.f};
  const int krow = wt * 16 + r16;
  const int ksw  = (krow & 7) << 4;

  for (int i = 0; i < 32; ++i) {
    __syncthreads();
    if (i < 31) {
      const int nb = (i + 1) & 1;
      const char* ksrc = (const char*)(Kg0 + (size_t)((i + 1) * 64 + srow) * D_MODEL)
                         + ((sch ^ ssw) << 4);
      load16(ksrc, KB_ + (nb << 13) + (wid << 10));
      const char* vsrc = (const char*)(Vg0 + (size_t)srow * SEQ + (i + 1) * 64)
                         + ((sch ^ ssw) << 4);
      load16(vsrc, VB_ + (nb << 13) + (wid << 10));
    }
    char* const Kt  = KB_ + ((i & 1) << 13);
    char* const Vtl = VB_ + ((i & 1) << 13);

    const bf16x8 kb0 = *(const bf16x8*)(Kt + krow * 128 + ((g * 16) ^ ksw));
    const bf16x8 kb1 = *(const bf16x8*)(Kt + krow * 128 + ((g * 16 + 64) ^ ksw));
    f32x4 c = {0.f, 0.f, 0.f, 0.f};
    c = __builtin_amdgcn_mfma_f32_16x16x32_bf16(qa0, kb0, c, 0, 0, 0);
    c = __builtin_amdgcn_mfma_f32_16x16x32_bf16(qa1, kb1, c, 0, 0, 0);

    const int tg = i * 64 + wt * 16 + r16;
    const int mk = mrow[tg];
    {
      const int qb_ = qh * 16 + g * 4;
      const int psw = ((qb_ >> 2) & 3) << 5;
      const int pb  = qb_ * 4096 + tg * 2;
      const float e0 = mk ? 0.f : __expf(c[0]);
      const float e1 = mk ? 0.f : __expf(c[1]);
      const float e2 = mk ? 0.f : __expf(c[2]);
      const float e3 = mk ? 0.f : __expf(c[3]);
      rs0 += e0; rs1 += e1; rs2 += e2; rs3 += e3;
      *(unsigned short*)(Pb + ((pb + 0 * 4096) ^ psw)) = f2bf(e0);
      *(unsigned short*)(Pb + ((pb + 1 * 4096) ^ psw)) = f2bf(e1);
      *(unsigned short*)(Pb + ((pb + 2 * 4096) ^ psw)) = f2bf(e2);
      *(unsigned short*)(Pb + ((pb + 3 * 4096) ^ psw)) = f2bf(e3);
    }

    asm volatile("s_waitcnt lgkmcnt(0)\n\ts_barrier" ::: "memory");

    {
      const int prow = qh * 16 + r16;
      const int psw  = ((prow >> 2) & 3) << 5;
      const int pbse = prow * 4096 + i * 128 + g * 16;
      const bf16x8 pa0 = *(const bf16x8*)(Pb + (pbse ^ psw));
      const bf16x8 pa1 = *(const bf16x8*)(Pb + ((pbse + 64) ^ psw));
      const bf16x8 vb0 = *(const bf16x8*)(Vtl + krow * 128 + ((g * 16) ^ ksw));
      const bf16x8 vb1 = *(const bf16x8*)(Vtl + krow * 128 + ((g * 16 + 64) ^ ksw));
      oacc = __builtin_amdgcn_mfma_f32_16x16x32_bf16(pa0, vb0, oacc, 0, 0, 0);
      oacc = __builtin_amdgcn_mfma_f32_16x16x32_bf16(pa1, vb1, oacc, 0, 0, 0);
    }
  }

  __syncthreads();
  float* red = (float*)KB_;
  rs0 += __shfl_xor(rs0, 1); rs0 += __shfl_xor(rs0, 2);
  rs0 += __shfl_xor(rs0, 4); rs0 += __shfl_xor(rs0, 8);
  rs1 += __shfl_xor(rs1, 1); rs1 += __shfl_xor(rs1, 2);
  rs1 += __shfl_xor(rs1, 4); rs1 += __shfl_xor(rs1, 8);
  rs2 += __shfl_xor(rs2, 1); rs2 += __shfl_xor(rs2, 2);
  rs2 += __shfl_xor(rs2, 4); rs2 += __shfl_xor(rs2, 8);
  rs3 += __shfl_xor(rs3, 1); rs3 += __shfl_xor(rs3, 2);
  rs3 += __shfl_xor(rs3, 4); rs3 += __shfl_xor(rs3, 8);
  if (r16 == 0) {
    red[wid * 16 + g * 4 + 0] = rs0;
    red[wid * 16 + g * 4 + 1] = rs1;
    red[wid * 16 + g * 4 + 2] = rs2;
    red[wid * 16 + g * 4 + 3] = rs3;
  }
  __syncthreads();

  {  // O write (normalized, bf16 hi/lo split)
    #pragma unroll
    for (int rr = 0; rr < 4; ++rr) {
      const int qt = g * 4 + rr;
      const float l = red[(qh * 4 + 0) * 16 + qt] + red[(qh * 4 + 1) * 16 + qt]
                    + red[(qh * 4 + 2) * 16 + qt] + red[(qh * 4 + 3) * 16 + qt];
      const size_t idx =
          (size_t)(b * SEQ + q0 + qh * 16 + qt) * D_MODEL + h * 64 + wt * 16 + r16;
      const float o = oacc[rr] / l;
      const unsigned short oh = f2bf(o);
      Oh[idx] = oh;
      Ol[idx] = f2bf(o - bf2f(oh));
    }
  }

  {  // attn write (normalized fp32, coalesced float4)
    #pragma unroll
    for (int rq = 0; rq < 4; ++rq) {
      const int q  = wid * 4 + rq;
      const int qt = q & 15, qh2 = q >> 4;
      const float l = red[(qh2 * 4 + 0) * 16 + qt] + red[(qh2 * 4 + 1) * 16 + qt]
                    + red[(qh2 * 4 + 2) * 16 + qt] + red[(qh2 * 4 + 3) * 16 + qt];
      const float inv = 1.f / l;
      const int psw = ((q >> 2) & 3) << 5;
      const char* prow = Pb + q * 4096;
      float* arow = attn + ((size_t)bh * SEQ + q0 + q) * SEQ;
      #pragma unroll
      for (int ch = 0; ch < 8; ++ch) {
        const int off = (ch * 512 + lane * 8) ^ psw;
        const ushort4 pv4 = *(const ushort4*)(prow + off);
        float4 o;
        o.x = bf2f(pv4.x) * inv;
        o.y = bf2f(pv4.y) * inv;
        o.z = bf2f(pv4.z) * inv;
        o.w = bf2f(pv4.w) * inv;
        *(float4*)&arow[ch * 256 + lane * 4] = o;
      }
    }
  }
}

// ---------------------------------------------------------------------------
extern "C" void kernel_launch(void* const* d_in, const int* in_sizes, int n_in,
                              void* d_out, int out_size, void* d_ws, size_t ws_size,
                              hipStream_t stream) {
  const float* v    = (const float*)d_in[0];
  const float* k    = (const float*)d_in[1];
  const float* q    = (const float*)d_in[2];
  const int*   mask = (const int*)  d_in[3];
  const float* Wq   = (const float*)d_in[4];
  const float* bq   = (const float*)d_in[5];
  const float* Wk   = (const float*)d_in[6];
  const float* bk   = (const float*)d_in[7];
  const float* Wv   = (const float*)d_in[8];
  const float* bv   = (const float*)d_in[9];
  const float* Wo   = (const float*)d_in[10];
  const float* bo   = (const float*)d_in[11];

  const size_t NTOK = (size_t)2 * SEQ;            // 4096 tokens
  const size_t TOKF = NTOK * D_MODEL;             // 4,194,304 elements
  const size_t WSZ  = (size_t)D_MODEL * D_MODEL;  // 1,048,576
  float* out  = (float*)d_out;
  float* attn = out + TOKF;

  unsigned short* qx   = (unsigned short*)d_ws;   // bf16 inputs
  unsigned short* kx   = qx + TOKF;
  unsigned short* vx   = kx + TOKF;
  unsigned short* Qbf  = vx + TOKF;               // projections
  unsigned short* Kbf  = Qbf + TOKF;
  unsigned short* Vtb  = Kbf + TOKF;
  unsigned short* Ohb  = Vtb + TOKF;              // attn O hi/lo
  unsigned short* Olb  = Ohb + TOKF;
  unsigned short* Wqt  = Olb + TOKF;              // transposed bf16 weights
  unsigned short* Wkt  = Wqt + WSZ;
  unsigned short* Wvt  = Wkt + WSZ;
  unsigned short* Woth = Wvt + WSZ;
  unsigned short* Wotl = Woth + WSZ;

  const int cvtg = (int)(TOKF / 4 / 256);         // 4096 blocks
  cvt_bf16<<<cvtg, 256, 0, stream>>>((const float4*)q, (ushort4*)qx);
  cvt_bf16<<<cvtg, 256, 0, stream>>>((const float4*)k, (ushort4*)kx);
  cvt_bf16<<<cvtg, 256, 0, stream>>>((const float4*)v, (ushort4*)vx);
  const dim3 wg(16, 16);
  wt_cvt<false><<<wg, 256, 0, stream>>>(Wq, Wqt, nullptr);
  wt_cvt<false><<<wg, 256, 0, stream>>>(Wk, Wkt, nullptr);
  wt_cvt<false><<<wg, 256, 0, stream>>>(Wv, Wvt, nullptr);
  wt_cvt<true> <<<wg, 256, 0, stream>>>(Wo, Woth, Wotl);

  gemm64<0><<<1024, 256, 0, stream>>>(qx, nullptr, Wqt, nullptr, bq, Qbf, 0.125f);
  gemm64<0><<<1024, 256, 0, stream>>>(kx, nullptr, Wkt, nullptr, bk, Kbf, 1.0f);
  gemm64<1><<<1024, 256, 0, stream>>>(vx, nullptr, Wvt, nullptr, bv, Vtb, 1.0f);

  attn_mfma<<<2048, 512, 0, stream>>>(Qbf, Kbf, Vtb, mask, attn, Ohb, Olb);

  gemm64<2><<<1024, 256, 0, stream>>>(Ohb, Olb, Woth, Wotl, bo, out, 1.0f);
}

// Round 4
// 331.431 us; speedup vs baseline: 10.5953x; 1.2208x over previous
//
#include <hip/hip_runtime.h>
#include <hip/hip_bf16.h>
#include <math.h>

#define D_MODEL 1024
#define SEQ     2048
#define NHEAD   16

typedef __attribute__((ext_vector_type(8))) short bf16x8;
typedef __attribute__((ext_vector_type(4))) float f32x4;
typedef const __attribute__((address_space(1))) unsigned int* gas_u32p;
typedef __attribute__((address_space(3))) unsigned int* las_u32p;

__device__ __forceinline__ void load16(const void* g, void* l) {
  __builtin_amdgcn_global_load_lds((gas_u32p)g, (las_u32p)l, 16, 0, 0);
}

__device__ __forceinline__ unsigned short f2bf(float f) {
  __hip_bfloat16 h = __float2bfloat16(f);
  return *(unsigned short*)&h;
}
__device__ __forceinline__ float bf2f(unsigned short u) {
  return __uint_as_float((unsigned)u << 16);
}

// ---------------------------------------------------------------------------
// fp32 -> bf16 elementwise (float4 -> ushort4)
// ---------------------------------------------------------------------------
__global__ __launch_bounds__(256) void cvt_bf16(
    const float4* __restrict__ in, ushort4* __restrict__ out) {
  const int i = blockIdx.x * 256 + threadIdx.x;
  const float4 f = in[i];
  ushort4 u;
  u.x = f2bf(f.x); u.y = f2bf(f.y); u.z = f2bf(f.z); u.w = f2bf(f.w);
  out[i] = u;
}

// ---------------------------------------------------------------------------
// W [1024 k][1024 n] fp32 -> Wt bf16 [n][k] (hi, and optionally lo part)
// ---------------------------------------------------------------------------
template <bool LO>
__global__ __launch_bounds__(256) void wt_cvt(
    const float* __restrict__ W, unsigned short* __restrict__ Wh,
    unsigned short* __restrict__ Wl) {
  __shared__ float t[64][65];
  const int tid = threadIdx.x;
  const int k0 = blockIdx.y * 64, n0 = blockIdx.x * 64;
  #pragma unroll
  for (int it = 0; it < 4; ++it) {
    const int r = it * 16 + (tid >> 4), c4 = (tid & 15) * 4;
    const float4 f = *(const float4*)&W[(size_t)(k0 + r) * D_MODEL + n0 + c4];
    t[r][c4 + 0] = f.x; t[r][c4 + 1] = f.y;
    t[r][c4 + 2] = f.z; t[r][c4 + 3] = f.w;
  }
  __syncthreads();
  #pragma unroll
  for (int it = 0; it < 4; ++it) {
    const int n = it * 16 + (tid >> 4), k4 = (tid & 15) * 4;
    float fs[4];
    fs[0] = t[k4 + 0][n]; fs[1] = t[k4 + 1][n];
    fs[2] = t[k4 + 2][n]; fs[3] = t[k4 + 3][n];
    ushort4 uh;
    uh.x = f2bf(fs[0]); uh.y = f2bf(fs[1]);
    uh.z = f2bf(fs[2]); uh.w = f2bf(fs[3]);
    *(ushort4*)&Wh[(size_t)(n0 + n) * D_MODEL + k0 + k4] = uh;
    if (LO) {
      ushort4 ul;
      ul.x = f2bf(fs[0] - bf2f(uh.x)); ul.y = f2bf(fs[1] - bf2f(uh.y));
      ul.z = f2bf(fs[2] - bf2f(uh.z)); ul.w = f2bf(fs[3] - bf2f(uh.w));
      *(ushort4*)&Wl[(size_t)(n0 + n) * D_MODEL + k0 + k4] = ul;
    }
  }
}

// ---------------------------------------------------------------------------
// bf16 MFMA GEMM, 64x64 tile, BK=64 (validated round 3).
// MODE 0: bf16 out *scale   MODE 1: per-head-transposed bf16 V
// MODE 2: fp32 out, split-precision (A*Bh + A*Bl + Al*Bh)
// ---------------------------------------------------------------------------
template <int MODE>
__global__ __launch_bounds__(256, 2) void gemm64(
    const unsigned short* __restrict__ A, const unsigned short* __restrict__ Al,
    const unsigned short* __restrict__ Bh, const unsigned short* __restrict__ Bl,
    const float* __restrict__ bias, void* __restrict__ outp, float scale) {
  constexpr int NT = (MODE == 2) ? 4 : 2;
  __shared__ char lds[NT * 8192 * 2];
  const int tid = threadIdx.x;
  const int lane = tid & 63, wid = tid >> 6;
  const int r16 = lane & 15, g = lane >> 4;
  const int bid = blockIdx.x;
  const int orig = (bid & 7) * 128 + (bid >> 3);
  const int bm = orig >> 4, bn = orig & 15;
  const int row0 = bm * 64, col0 = bn * 64;
  const int wm = wid >> 1, wn = wid & 1;

  const int srow = tid >> 3, sch = tid & 7;

  const unsigned short* Ag  = A + (size_t)row0 * D_MODEL;
  const unsigned short* Bg  = Bh + (size_t)col0 * D_MODEL;
  const unsigned short* Alg = (MODE == 2) ? Al + (size_t)row0 * D_MODEL : nullptr;
  const unsigned short* Blg = (MODE == 2) ? Bl + (size_t)col0 * D_MODEL : nullptr;

  auto stage_tile = [&](const unsigned short* g0, char* dst, int k0) {
    #pragma unroll
    for (int c = 0; c < 2; ++c) {
      const int r = c * 32 + srow;
      const unsigned short* src =
          g0 + (size_t)r * D_MODEL + k0 + ((sch ^ (r & 7)) << 3);
      load16(src, dst + c * 4096 + tid * 16);
    }
  };
  auto stage = [&](int buf, int k0) {
    char* base = lds + buf * (NT * 8192);
    stage_tile(Ag, base, k0);
    stage_tile(Bg, base + 8192, k0);
    if constexpr (MODE == 2) {
      stage_tile(Alg, base + 16384, k0);
      stage_tile(Blg, base + 24576, k0);
    }
  };

  stage(0, 0);
  f32x4 acc[2][2] = {};

  for (int s = 0; s < 16; ++s) {
    __syncthreads();
    if (s < 15) stage((s + 1) & 1, (s + 1) * 64);
    const char* base = lds + (s & 1) * (NT * 8192);
    #pragma unroll
    for (int kk = 0; kk < 2; ++kk) {
      bf16x8 a[2], b[2];
      #pragma unroll
      for (int mi = 0; mi < 2; ++mi) {
        const int r = wm * 32 + mi * 16 + r16;
        a[mi] = *(const bf16x8*)(base + r * 128 + (((g + kk * 4) ^ (r & 7)) << 4));
      }
      #pragma unroll
      for (int ni = 0; ni < 2; ++ni) {
        const int r = wn * 32 + ni * 16 + r16;
        b[ni] = *(const bf16x8*)(base + 8192 + r * 128 +
                                 (((g + kk * 4) ^ (r & 7)) << 4));
      }
      #pragma unroll
      for (int mi = 0; mi < 2; ++mi)
        #pragma unroll
        for (int ni = 0; ni < 2; ++ni)
          acc[mi][ni] = __builtin_amdgcn_mfma_f32_16x16x32_bf16(
              a[mi], b[ni], acc[mi][ni], 0, 0, 0);
      if constexpr (MODE == 2) {
        bf16x8 al[2], bl[2];
        #pragma unroll
        for (int mi = 0; mi < 2; ++mi) {
          const int r = wm * 32 + mi * 16 + r16;
          al[mi] = *(const bf16x8*)(base + 16384 + r * 128 +
                                    (((g + kk * 4) ^ (r & 7)) << 4));
        }
        #pragma unroll
        for (int ni = 0; ni < 2; ++ni) {
          const int r = wn * 32 + ni * 16 + r16;
          bl[ni] = *(const bf16x8*)(base + 24576 + r * 128 +
                                    (((g + kk * 4) ^ (r & 7)) << 4));
        }
        #pragma unroll
        for (int mi = 0; mi < 2; ++mi)
          #pragma unroll
          for (int ni = 0; ni < 2; ++ni) {
            acc[mi][ni] = __builtin_amdgcn_mfma_f32_16x16x32_bf16(
                a[mi], bl[ni], acc[mi][ni], 0, 0, 0);
            acc[mi][ni] = __builtin_amdgcn_mfma_f32_16x16x32_bf16(
                al[mi], b[ni], acc[mi][ni], 0, 0, 0);
          }
      }
    }
  }

  if constexpr (MODE == 0) {
    unsigned short* C = (unsigned short*)outp;
    #pragma unroll
    for (int mi = 0; mi < 2; ++mi)
      #pragma unroll
      for (int ni = 0; ni < 2; ++ni) {
        const int col = col0 + wn * 32 + ni * 16 + r16;
        const float bb = bias[col];
        const int rowb = row0 + wm * 32 + mi * 16 + g * 4;
        #pragma unroll
        for (int j = 0; j < 4; ++j)
          C[(size_t)(rowb + j) * D_MODEL + col] =
              f2bf((acc[mi][ni][j] + bb) * scale);
      }
  } else if constexpr (MODE == 1) {
    unsigned short* Vt = (unsigned short*)outp;
    #pragma unroll
    for (int mi = 0; mi < 2; ++mi)
      #pragma unroll
      for (int ni = 0; ni < 2; ++ni) {
        const int col = col0 + wn * 32 + ni * 16 + r16;
        const int hh = col >> 6, dd = col & 63;
        const float bb = bias[col];
        const int rowb = row0 + wm * 32 + mi * 16 + g * 4;
        const int b_ = rowb >> 11, tt = rowb & 2047;
        ushort4 u;
        u.x = f2bf(acc[mi][ni][0] + bb);
        u.y = f2bf(acc[mi][ni][1] + bb);
        u.z = f2bf(acc[mi][ni][2] + bb);
        u.w = f2bf(acc[mi][ni][3] + bb);
        *(ushort4*)&Vt[((size_t)((b_ * NHEAD + hh) * 64 + dd)) * SEQ + tt] = u;
      }
  } else {
    float* O = (float*)outp;
    #pragma unroll
    for (int mi = 0; mi < 2; ++mi)
      #pragma unroll
      for (int ni = 0; ni < 2; ++ni) {
        const int col = col0 + wn * 32 + ni * 16 + r16;
        const float bb = bias[col];
        const int rowb = row0 + wm * 32 + mi * 16 + g * 4;
        #pragma unroll
        for (int j = 0; j < 4; ++j)
          O[(size_t)(rowb + j) * D_MODEL + col] = acc[mi][ni][j] + bb;
      }
  }
}

// ---------------------------------------------------------------------------
// Two-pass MFMA attention. Block = (b,h, 32 q-rows), 512 threads (8 waves).
// Pass 1: stream K (ring-4, counted vmcnt), QK^T -> exp -> rowsums (regs).
// Pass 2: stream K+V, QK^T again -> normalized p -> fp32 attn store in-loop
//         + bf16 P-tile in LDS -> PV MFMA (O pre-normalized).
// LDS 68.5 KB -> 2 blocks/CU. Mask pre-packed per-lane in a 32-bit reg so
// the loop has exactly {2 loads + 4 stores}/iter in the vmcnt FIFO.
// ---------------------------------------------------------------------------
__global__ __launch_bounds__(512, 4) void attn_2pass(
    const unsigned short* __restrict__ Qb,   // bf16 [4096][1024], pre-scaled /8
    const unsigned short* __restrict__ Kb,   // bf16 [4096][1024]
    const unsigned short* __restrict__ Vt,   // bf16 [32*64][2048]
    const int* __restrict__ mask,            // [2][2048]
    float* __restrict__ attn,                // [32][2048][2048]
    unsigned short* __restrict__ Oh,         // bf16 hi [4096][1024]
    unsigned short* __restrict__ Ol) {       // bf16 lo [4096][1024]
  __shared__ char lds[70144];
  char* const Kbuf = lds;                    // 4 x 8192
  char* const Vbuf = lds + 32768;            // 4 x 8192
  char* const Pt   = lds + 65536;            // 4096 (Q staging, then P tile)
  float* const red = (float*)(lds + 69632);  // 8 waves x 16 q

  const int tid  = threadIdx.x;
  const int lane = tid & 63;
  const int wid  = tid >> 6;
  const int r16  = lane & 15;
  const int g    = lane >> 4;
  const int qh   = wid >> 2;                 // q half (0..1)
  const int wt   = wid & 3;                  // t window (QK) / d window (PV)

  const int bid  = blockIdx.x;
  const int orig = (bid & 7) * 256 + (bid >> 3);   // XCD swizzle
  const int bh   = orig >> 6;
  const int qblk = orig & 63;
  const int b    = bh >> 4, h = bh & 15;
  const int q0   = qblk * 32;

  const unsigned short* Kg0 = Kb + (size_t)(b * SEQ) * D_MODEL + h * 64;
  const unsigned short* Qg0 = Qb + (size_t)(b * SEQ + q0) * D_MODEL + h * 64;
  const unsigned short* Vg0 = Vt + (size_t)(bh * 64) * SEQ;
  const int* mrow = mask + b * SEQ;

  const int srow = tid >> 3, sch = tid & 7;
  const int ssw  = srow & 7;

  auto stageK = [&](int t) {
    const char* src = (const char*)(Kg0 + (size_t)(t * 64 + srow) * D_MODEL)
                      + ((sch ^ ssw) << 4);
    load16(src, Kbuf + ((t & 3) << 13) + (wid << 10));
  };
  auto stageV = [&](int t) {
    const char* src = (const char*)(Vg0 + (size_t)srow * SEQ + t * 64)
                      + ((sch ^ ssw) << 4);
    load16(src, Vbuf + ((t & 3) << 13) + (wid << 10));
  };

  // per-lane mask bits for t = i*64 + wt*16 + r16
  const int tb = wt * 16 + r16;
  unsigned mbits = 0;
  #pragma unroll 4
  for (int i = 0; i < 32; ++i)
    mbits |= (mrow[i * 64 + tb] ? 1u : 0u) << i;

  // ---- prologue: Q + K tiles 0..2 ---------------------------------------
  if (tid < 256) {
    const char* qsrc = (const char*)(Qg0 + (size_t)srow * D_MODEL)
                       + ((sch ^ ssw) << 4);
    load16(qsrc, Pt + (wid << 10));
  }
  stageK(0); stageK(1); stageK(2);
  __syncthreads();

  bf16x8 qa0, qa1;
  {
    const int row = qh * 16 + r16;
    const int sw = (row & 7) << 4;
    qa0 = *(const bf16x8*)(Pt + row * 128 + ((g * 16) ^ sw));
    qa1 = *(const bf16x8*)(Pt + row * 128 + ((g * 16 + 64) ^ sw));
  }

  const int krow = wt * 16 + r16;
  const int ksw  = (krow & 7) << 4;

  // ---- pass 1: rowsums ---------------------------------------------------
  float rs0 = 0.f, rs1 = 0.f, rs2 = 0.f, rs3 = 0.f;
  for (int i = 0; i < 32; ++i) {
    if (i < 30)
      asm volatile("s_waitcnt vmcnt(2)\n\ts_barrier" ::: "memory");
    else if (i == 30)
      asm volatile("s_waitcnt vmcnt(1)\n\ts_barrier" ::: "memory");
    else
      asm volatile("s_waitcnt vmcnt(0)\n\ts_barrier" ::: "memory");
    if (i + 3 < 32) stageK(i + 3);
    const char* Kt = Kbuf + ((i & 3) << 13);
    const bf16x8 kb0 = *(const bf16x8*)(Kt + krow * 128 + ((g * 16) ^ ksw));
    const bf16x8 kb1 = *(const bf16x8*)(Kt + krow * 128 + ((g * 16 + 64) ^ ksw));
    f32x4 c = {0.f, 0.f, 0.f, 0.f};
    __builtin_amdgcn_s_setprio(1);
    c = __builtin_amdgcn_mfma_f32_16x16x32_bf16(qa0, kb0, c, 0, 0, 0);
    c = __builtin_amdgcn_mfma_f32_16x16x32_bf16(qa1, kb1, c, 0, 0, 0);
    __builtin_amdgcn_s_setprio(0);
    if (!((mbits >> i) & 1u)) {
      rs0 += __expf(c[0]); rs1 += __expf(c[1]);
      rs2 += __expf(c[2]); rs3 += __expf(c[3]);
    }
  }

  // ---- rowsum reduction --------------------------------------------------
  rs0 += __shfl_xor(rs0, 1); rs0 += __shfl_xor(rs0, 2);
  rs0 += __shfl_xor(rs0, 4); rs0 += __shfl_xor(rs0, 8);
  rs1 += __shfl_xor(rs1, 1); rs1 += __shfl_xor(rs1, 2);
  rs1 += __shfl_xor(rs1, 4); rs1 += __shfl_xor(rs1, 8);
  rs2 += __shfl_xor(rs2, 1); rs2 += __shfl_xor(rs2, 2);
  rs2 += __shfl_xor(rs2, 4); rs2 += __shfl_xor(rs2, 8);
  rs3 += __shfl_xor(rs3, 1); rs3 += __shfl_xor(rs3, 2);
  rs3 += __shfl_xor(rs3, 4); rs3 += __shfl_xor(rs3, 8);
  if (r16 == 0) {
    red[wid * 16 + g * 4 + 0] = rs0;
    red[wid * 16 + g * 4 + 1] = rs1;
    red[wid * 16 + g * 4 + 2] = rs2;
    red[wid * 16 + g * 4 + 3] = rs3;
  }
  __syncthreads();

  float inv[4];
  #pragma unroll
  for (int j = 0; j < 4; ++j) {
    const int qt = g * 4 + j;
    inv[j] = 1.f / (red[(qh * 4 + 0) * 16 + qt] + red[(qh * 4 + 1) * 16 + qt] +
                    red[(qh * 4 + 2) * 16 + qt] + red[(qh * 4 + 3) * 16 + qt]);
  }

  // ---- pass 2 prologue ---------------------------------------------------
  stageK(0); stageV(0); stageK(1); stageV(1); stageK(2); stageV(2);
  __syncthreads();

  f32x4 oacc = {0.f, 0.f, 0.f, 0.f};
  float* const arow0 = attn + ((size_t)bh * SEQ + q0 + qh * 16 + g * 4) * SEQ;
  const int prow0 = qh * 16 + g * 4;
  const int parow = qh * 16 + r16;
  const int pasw  = (parow & 7) << 4;

  for (int i = 0; i < 32; ++i) {
    // steady state vmcnt FIFO newer than tile-i loads:
    // S(i-3)4 + L(i+1)2 + S(i-2)4 + L(i+2)2 + S(i-1)4 = 16
    if (i < 30)
      asm volatile("s_waitcnt vmcnt(16)\n\ts_barrier" ::: "memory");
    else if (i == 30)
      asm volatile("s_waitcnt vmcnt(14)\n\ts_barrier" ::: "memory");
    else
      asm volatile("s_waitcnt vmcnt(12)\n\ts_barrier" ::: "memory");
    if (i + 3 < 32) { stageK(i + 3); stageV(i + 3); }

    const char* Kt = Kbuf + ((i & 3) << 13);
    const bf16x8 kb0 = *(const bf16x8*)(Kt + krow * 128 + ((g * 16) ^ ksw));
    const bf16x8 kb1 = *(const bf16x8*)(Kt + krow * 128 + ((g * 16 + 64) ^ ksw));
    f32x4 c = {0.f, 0.f, 0.f, 0.f};
    __builtin_amdgcn_s_setprio(1);
    c = __builtin_amdgcn_mfma_f32_16x16x32_bf16(qa0, kb0, c, 0, 0, 0);
    c = __builtin_amdgcn_mfma_f32_16x16x32_bf16(qa1, kb1, c, 0, 0, 0);
    __builtin_amdgcn_s_setprio(0);

    const int tg = i * 64 + tb;
    const unsigned mk = (mbits >> i) & 1u;
    const float p0 = mk ? 0.f : __expf(c[0]) * inv[0];
    const float p1 = mk ? 0.f : __expf(c[1]) * inv[1];
    const float p2 = mk ? 0.f : __expf(c[2]) * inv[2];
    const float p3 = mk ? 0.f : __expf(c[3]) * inv[3];

    // normalized attn, written in-loop (4 stores -> vmcnt FIFO)
    arow0[0 * SEQ + tg] = p0;
    arow0[1 * SEQ + tg] = p1;
    arow0[2 * SEQ + tg] = p2;
    arow0[3 * SEQ + tg] = p3;

    // P tile for PV (bf16, XOR-swizzled rows)
    *(unsigned short*)(Pt + (((prow0 + 0) * 128 + tb * 2) ^ (((prow0 + 0) & 7) << 4))) = f2bf(p0);
    *(unsigned short*)(Pt + (((prow0 + 1) * 128 + tb * 2) ^ (((prow0 + 1) & 7) << 4))) = f2bf(p1);
    *(unsigned short*)(Pt + (((prow0 + 2) * 128 + tb * 2) ^ (((prow0 + 2) & 7) << 4))) = f2bf(p2);
    *(unsigned short*)(Pt + (((prow0 + 3) * 128 + tb * 2) ^ (((prow0 + 3) & 7) << 4))) = f2bf(p3);

    asm volatile("s_waitcnt lgkmcnt(0)\n\ts_barrier" ::: "memory");

    const char* Vtl = Vbuf + ((i & 3) << 13);
    const bf16x8 pa0 = *(const bf16x8*)(Pt + parow * 128 + ((g * 16) ^ pasw));
    const bf16x8 pa1 = *(const bf16x8*)(Pt + parow * 128 + ((g * 16 + 64) ^ pasw));
    const bf16x8 vb0 = *(const bf16x8*)(Vtl + krow * 128 + ((g * 16) ^ ksw));
    const bf16x8 vb1 = *(const bf16x8*)(Vtl + krow * 128 + ((g * 16 + 64) ^ ksw));
    __builtin_amdgcn_s_setprio(1);
    oacc = __builtin_amdgcn_mfma_f32_16x16x32_bf16(pa0, vb0, oacc, 0, 0, 0);
    oacc = __builtin_amdgcn_mfma_f32_16x16x32_bf16(pa1, vb1, oacc, 0, 0, 0);
    __builtin_amdgcn_s_setprio(0);
  }

  // ---- O epilogue (already normalized), bf16 hi/lo -----------------------
  #pragma unroll
  for (int rr = 0; rr < 4; ++rr) {
    const size_t idx = (size_t)(b * SEQ + q0 + qh * 16 + g * 4 + rr) * D_MODEL
                       + h * 64 + wt * 16 + r16;
    const float o = oacc[rr];
    const unsigned short ohv = f2bf(o);
    Oh[idx] = ohv;
    Ol[idx] = f2bf(o - bf2f(ohv));
  }
}

// ---------------------------------------------------------------------------
extern "C" void kernel_launch(void* const* d_in, const int* in_sizes, int n_in,
                              void* d_out, int out_size, void* d_ws, size_t ws_size,
                              hipStream_t stream) {
  const float* v    = (const float*)d_in[0];
  const float* k    = (const float*)d_in[1];
  const float* q    = (const float*)d_in[2];
  const int*   mask = (const int*)  d_in[3];
  const float* Wq   = (const float*)d_in[4];
  const float* bq   = (const float*)d_in[5];
  const float* Wk   = (const float*)d_in[6];
  const float* bk   = (const float*)d_in[7];
  const float* Wv   = (const float*)d_in[8];
  const float* bv   = (const float*)d_in[9];
  const float* Wo   = (const float*)d_in[10];
  const float* bo   = (const float*)d_in[11];

  const size_t NTOK = (size_t)2 * SEQ;            // 4096 tokens
  const size_t TOKF = NTOK * D_MODEL;             // 4,194,304 elements
  const size_t WSZ  = (size_t)D_MODEL * D_MODEL;  // 1,048,576
  float* out  = (float*)d_out;
  float* attn = out + TOKF;

  unsigned short* qx   = (unsigned short*)d_ws;   // bf16 inputs
  unsigned short* kx   = qx + TOKF;
  unsigned short* vx   = kx + TOKF;
  unsigned short* Qbf  = vx + TOKF;               // projections
  unsigned short* Kbf  = Qbf + TOKF;
  unsigned short* Vtb  = Kbf + TOKF;
  unsigned short* Ohb  = Vtb + TOKF;              // attn O hi/lo
  unsigned short* Olb  = Ohb + TOKF;
  unsigned short* Wqt  = Olb + TOKF;              // transposed bf16 weights
  unsigned short* Wkt  = Wqt + WSZ;
  unsigned short* Wvt  = Wkt + WSZ;
  unsigned short* Woth = Wvt + WSZ;
  unsigned short* Wotl = Woth + WSZ;

  const int cvtg = (int)(TOKF / 4 / 256);         // 4096 blocks
  cvt_bf16<<<cvtg, 256, 0, stream>>>((const float4*)q, (ushort4*)qx);
  cvt_bf16<<<cvtg, 256, 0, stream>>>((const float4*)k, (ushort4*)kx);
  cvt_bf16<<<cvtg, 256, 0, stream>>>((const float4*)v, (ushort4*)vx);
  const dim3 wg(16, 16);
  wt_cvt<false><<<wg, 256, 0, stream>>>(Wq, Wqt, nullptr);
  wt_cvt<false><<<wg, 256, 0, stream>>>(Wk, Wkt, nullptr);
  wt_cvt<false><<<wg, 256, 0, stream>>>(Wv, Wvt, nullptr);
  wt_cvt<true> <<<wg, 256, 0, stream>>>(Wo, Woth, Wotl);

  gemm64<0><<<1024, 256, 0, stream>>>(qx, nullptr, Wqt, nullptr, bq, Qbf, 0.125f);
  gemm64<0><<<1024, 256, 0, stream>>>(kx, nullptr, Wkt, nullptr, bk, Kbf, 1.0f);
  gemm64<1><<<1024, 256, 0, stream>>>(vx, nullptr, Wvt, nullptr, bv, Vtb, 1.0f);

  attn_2pass<<<2048, 512, 0, stream>>>(Qbf, Kbf, Vtb, mask, attn, Ohb, Olb);

  gemm64<2><<<1024, 256, 0, stream>>>(Ohb, Olb, Woth, Wotl, bo, out, 1.0f);
}

// Round 5
// 331.129 us; speedup vs baseline: 10.6049x; 1.0009x over previous
//
#include <hip/hip_runtime.h>
#include <hip/hip_bf16.h>
#include <math.h>

#define D_MODEL 1024
#define SEQ     2048
#define NHEAD   16

typedef __attribute__((ext_vector_type(8))) short bf16x8;
typedef __attribute__((ext_vector_type(4))) float f32x4;
typedef const __attribute__((address_space(1))) unsigned int* gas_u32p;
typedef __attribute__((address_space(3))) unsigned int* las_u32p;

__device__ __forceinline__ void load16(const void* g, void* l) {
  __builtin_amdgcn_global_load_lds((gas_u32p)g, (las_u32p)l, 16, 0, 0);
}

__device__ __forceinline__ unsigned short f2bf(float f) {
  __hip_bfloat16 h = __float2bfloat16(f);
  return *(unsigned short*)&h;
}
__device__ __forceinline__ float bf2f(unsigned short u) {
  return __uint_as_float((unsigned)u << 16);
}

// ---------------------------------------------------------------------------
// fp32 -> bf16 elementwise (float4 -> ushort4)
// ---------------------------------------------------------------------------
__global__ __launch_bounds__(256) void cvt_bf16(
    const float4* __restrict__ in, ushort4* __restrict__ out) {
  const int i = blockIdx.x * 256 + threadIdx.x;
  const float4 f = in[i];
  ushort4 u;
  u.x = f2bf(f.x); u.y = f2bf(f.y); u.z = f2bf(f.z); u.w = f2bf(f.w);
  out[i] = u;
}

// ---------------------------------------------------------------------------
// W [1024 k][1024 n] fp32 -> Wt bf16 [n][k] (hi, and optionally lo part)
// ---------------------------------------------------------------------------
template <bool LO>
__global__ __launch_bounds__(256) void wt_cvt(
    const float* __restrict__ W, unsigned short* __restrict__ Wh,
    unsigned short* __restrict__ Wl) {
  __shared__ float t[64][65];
  const int tid = threadIdx.x;
  const int k0 = blockIdx.y * 64, n0 = blockIdx.x * 64;
  #pragma unroll
  for (int it = 0; it < 4; ++it) {
    const int r = it * 16 + (tid >> 4), c4 = (tid & 15) * 4;
    const float4 f = *(const float4*)&W[(size_t)(k0 + r) * D_MODEL + n0 + c4];
    t[r][c4 + 0] = f.x; t[r][c4 + 1] = f.y;
    t[r][c4 + 2] = f.z; t[r][c4 + 3] = f.w;
  }
  __syncthreads();
  #pragma unroll
  for (int it = 0; it < 4; ++it) {
    const int n = it * 16 + (tid >> 4), k4 = (tid & 15) * 4;
    float fs[4];
    fs[0] = t[k4 + 0][n]; fs[1] = t[k4 + 1][n];
    fs[2] = t[k4 + 2][n]; fs[3] = t[k4 + 3][n];
    ushort4 uh;
    uh.x = f2bf(fs[0]); uh.y = f2bf(fs[1]);
    uh.z = f2bf(fs[2]); uh.w = f2bf(fs[3]);
    *(ushort4*)&Wh[(size_t)(n0 + n) * D_MODEL + k0 + k4] = uh;
    if (LO) {
      ushort4 ul;
      ul.x = f2bf(fs[0] - bf2f(uh.x)); ul.y = f2bf(fs[1] - bf2f(uh.y));
      ul.z = f2bf(fs[2] - bf2f(uh.z)); ul.w = f2bf(fs[3] - bf2f(uh.w));
      *(ushort4*)&Wl[(size_t)(n0 + n) * D_MODEL + k0 + k4] = ul;
    }
  }
}

// ---------------------------------------------------------------------------
// bf16 MFMA GEMM, 128x64 tile, BK=64, 512 threads (8 waves: 4 wm x 2 wn),
// grid 512 blocks -> 2 blocks/CU. MODE 0: bf16 out*scale. MODE 1: Vt.
// ---------------------------------------------------------------------------
template <int MODE>
__global__ __launch_bounds__(512, 4) void gemm128(
    const unsigned short* __restrict__ A, const unsigned short* __restrict__ B,
    const float* __restrict__ bias, void* __restrict__ outp, float scale) {
  __shared__ char lds[49152];                 // 2 x (16K A + 8K B)
  const int tid = threadIdx.x;
  const int lane = tid & 63, wid = tid >> 6;
  const int r16 = lane & 15, g = lane >> 4;
  const int bid = blockIdx.x;
  const int orig = (bid & 7) * 64 + (bid >> 3);   // XCD swizzle (512%8==0)
  const int bm = orig >> 4, bn = orig & 15;
  const int row0 = bm * 128, col0 = bn * 64;
  const int wm = wid >> 1, wn = wid & 1;

  const unsigned short* Ag = A + (size_t)row0 * D_MODEL;
  const unsigned short* Bg = B + (size_t)col0 * D_MODEL;

  auto stage = [&](int buf, int k0) {
    char* base = lds + buf * 24576;
    #pragma unroll
    for (int c = 0; c < 2; ++c) {             // A: 128 rows x 64 k
      const int idx = c * 512 + tid;
      const int r = idx >> 3, ch = idx & 7;
      load16(Ag + (size_t)r * D_MODEL + k0 + ((ch ^ (r & 7)) << 3),
             base + idx * 16);
    }
    {                                          // B: 64 rows x 64 k
      const int r = tid >> 3, ch = tid & 7;
      load16(Bg + (size_t)r * D_MODEL + k0 + ((ch ^ (r & 7)) << 3),
             base + 16384 + tid * 16);
    }
  };

  stage(0, 0);
  f32x4 acc[2][2] = {};

  for (int s = 0; s < 16; ++s) {
    __syncthreads();
    if (s < 15) stage((s + 1) & 1, (s + 1) * 64);
    const char* base = lds + (s & 1) * 24576;
    #pragma unroll
    for (int kk = 0; kk < 2; ++kk) {
      bf16x8 a[2], b[2];
      #pragma unroll
      for (int mi = 0; mi < 2; ++mi) {
        const int r = wm * 32 + mi * 16 + r16;
        a[mi] = *(const bf16x8*)(base + r * 128 + (((g + kk * 4) ^ (r & 7)) << 4));
      }
      #pragma unroll
      for (int ni = 0; ni < 2; ++ni) {
        const int r = wn * 32 + ni * 16 + r16;
        b[ni] = *(const bf16x8*)(base + 16384 + r * 128 +
                                 (((g + kk * 4) ^ (r & 7)) << 4));
      }
      #pragma unroll
      for (int mi = 0; mi < 2; ++mi)
        #pragma unroll
        for (int ni = 0; ni < 2; ++ni)
          acc[mi][ni] = __builtin_amdgcn_mfma_f32_16x16x32_bf16(
              a[mi], b[ni], acc[mi][ni], 0, 0, 0);
    }
  }

  if constexpr (MODE == 0) {
    unsigned short* C = (unsigned short*)outp;
    #pragma unroll
    for (int mi = 0; mi < 2; ++mi)
      #pragma unroll
      for (int ni = 0; ni < 2; ++ni) {
        const int col = col0 + wn * 32 + ni * 16 + r16;
        const float bb = bias[col];
        const int rowb = row0 + wm * 32 + mi * 16 + g * 4;
        #pragma unroll
        for (int j = 0; j < 4; ++j)
          C[(size_t)(rowb + j) * D_MODEL + col] =
              f2bf((acc[mi][ni][j] + bb) * scale);
      }
  } else {
    unsigned short* Vt = (unsigned short*)outp;
    #pragma unroll
    for (int mi = 0; mi < 2; ++mi)
      #pragma unroll
      for (int ni = 0; ni < 2; ++ni) {
        const int col = col0 + wn * 32 + ni * 16 + r16;
        const int hh = col >> 6, dd = col & 63;
        const float bb = bias[col];
        const int rowb = row0 + wm * 32 + mi * 16 + g * 4;
        const int b_ = rowb >> 11, tt = rowb & 2047;
        ushort4 u;
        u.x = f2bf(acc[mi][ni][0] + bb);
        u.y = f2bf(acc[mi][ni][1] + bb);
        u.z = f2bf(acc[mi][ni][2] + bb);
        u.w = f2bf(acc[mi][ni][3] + bb);
        *(ushort4*)&Vt[((size_t)((b_ * NHEAD + hh) * 64 + dd)) * SEQ + tt] = u;
      }
  }
}

// ---------------------------------------------------------------------------
// bf16 MFMA GEMM 64x64, split-precision final: out = A*Bh + A*Bl + Al*Bh + bias
// (validated round 3)
// ---------------------------------------------------------------------------
__global__ __launch_bounds__(256, 2) void gemm64s(
    const unsigned short* __restrict__ A, const unsigned short* __restrict__ Al,
    const unsigned short* __restrict__ Bh, const unsigned short* __restrict__ Bl,
    const float* __restrict__ bias, float* __restrict__ O) {
  __shared__ char lds[65536];
  const int tid = threadIdx.x;
  const int lane = tid & 63, wid = tid >> 6;
  const int r16 = lane & 15, g = lane >> 4;
  const int bid = blockIdx.x;
  const int orig = (bid & 7) * 128 + (bid >> 3);
  const int bm = orig >> 4, bn = orig & 15;
  const int row0 = bm * 64, col0 = bn * 64;
  const int wm = wid >> 1, wn = wid & 1;
  const int srow = tid >> 3, sch = tid & 7;

  const unsigned short* Ag  = A + (size_t)row0 * D_MODEL;
  const unsigned short* Bg  = Bh + (size_t)col0 * D_MODEL;
  const unsigned short* Alg = Al + (size_t)row0 * D_MODEL;
  const unsigned short* Blg = Bl + (size_t)col0 * D_MODEL;

  auto stage_tile = [&](const unsigned short* g0, char* dst, int k0) {
    #pragma unroll
    for (int c = 0; c < 2; ++c) {
      const int r = c * 32 + srow;
      load16(g0 + (size_t)r * D_MODEL + k0 + ((sch ^ (r & 7)) << 3),
             dst + c * 4096 + tid * 16);
    }
  };
  auto stage = [&](int buf, int k0) {
    char* base = lds + buf * 32768;
    stage_tile(Ag, base, k0);
    stage_tile(Bg, base + 8192, k0);
    stage_tile(Alg, base + 16384, k0);
    stage_tile(Blg, base + 24576, k0);
  };

  stage(0, 0);
  f32x4 acc[2][2] = {};

  for (int s = 0; s < 16; ++s) {
    __syncthreads();
    if (s < 15) stage((s + 1) & 1, (s + 1) * 64);
    const char* base = lds + (s & 1) * 32768;
    #pragma unroll
    for (int kk = 0; kk < 2; ++kk) {
      bf16x8 a[2], b[2], al[2], bl[2];
      #pragma unroll
      for (int mi = 0; mi < 2; ++mi) {
        const int r = wm * 32 + mi * 16 + r16;
        const int off = r * 128 + (((g + kk * 4) ^ (r & 7)) << 4);
        a[mi]  = *(const bf16x8*)(base + off);
        al[mi] = *(const bf16x8*)(base + 16384 + off);
      }
      #pragma unroll
      for (int ni = 0; ni < 2; ++ni) {
        const int r = wn * 32 + ni * 16 + r16;
        const int off = r * 128 + (((g + kk * 4) ^ (r & 7)) << 4);
        b[ni]  = *(const bf16x8*)(base + 8192 + off);
        bl[ni] = *(const bf16x8*)(base + 24576 + off);
      }
      #pragma unroll
      for (int mi = 0; mi < 2; ++mi)
        #pragma unroll
        for (int ni = 0; ni < 2; ++ni) {
          acc[mi][ni] = __builtin_amdgcn_mfma_f32_16x16x32_bf16(
              a[mi], b[ni], acc[mi][ni], 0, 0, 0);
          acc[mi][ni] = __builtin_amdgcn_mfma_f32_16x16x32_bf16(
              a[mi], bl[ni], acc[mi][ni], 0, 0, 0);
          acc[mi][ni] = __builtin_amdgcn_mfma_f32_16x16x32_bf16(
              al[mi], b[ni], acc[mi][ni], 0, 0, 0);
        }
    }
  }

  #pragma unroll
  for (int mi = 0; mi < 2; ++mi)
    #pragma unroll
    for (int ni = 0; ni < 2; ++ni) {
      const int col = col0 + wn * 32 + ni * 16 + r16;
      const float bb = bias[col];
      const int rowb = row0 + wm * 32 + mi * 16 + g * 4;
      #pragma unroll
      for (int j = 0; j < 4; ++j)
        O[(size_t)(rowb + j) * D_MODEL + col] = acc[mi][ni][j] + bb;
    }
}

// ---------------------------------------------------------------------------
// Two-pass MFMA attention. Block = (b,h, 32 q-rows), 512 threads (8 waves).
// Pass 1: stream K (ring-4, counted vmcnt), QK^T -> exp -> rowsums.
// Pass 2: stream K+V, QK^T -> normalized bf16 P tile in LDS -> PV MFMA,
//         attn written via coalesced LDS readback (1 float4 store/thread/iter).
// vmcnt FIFO/iter: 2 loads + 1 store -> steady vmcnt(7), tail 5/3.
// ---------------------------------------------------------------------------
__global__ __launch_bounds__(512, 4) void attn_2pass(
    const unsigned short* __restrict__ Qb,   // bf16 [4096][1024], pre-scaled /8
    const unsigned short* __restrict__ Kb,   // bf16 [4096][1024]
    const unsigned short* __restrict__ Vt,   // bf16 [32*64][2048]
    const int* __restrict__ mask,            // [2][2048]
    float* __restrict__ attn,                // [32][2048][2048]
    unsigned short* __restrict__ Oh,         // bf16 hi [4096][1024]
    unsigned short* __restrict__ Ol) {       // bf16 lo [4096][1024]
  __shared__ char lds[70144];
  char* const Kbuf = lds;                    // 4 x 8192
  char* const Vbuf = lds + 32768;            // 4 x 8192
  char* const Pt   = lds + 65536;            // 4096 (Q staging, then P tile)
  float* const red = (float*)(lds + 69632);  // 8 waves x 16 q

  const int tid  = threadIdx.x;
  const int lane = tid & 63;
  const int wid  = tid >> 6;
  const int r16  = lane & 15;
  const int g    = lane >> 4;
  const int qh   = wid >> 2;                 // q half (0..1)
  const int wt   = wid & 3;                  // t window (QK) / d window (PV)

  const int bid  = blockIdx.x;
  const int orig = (bid & 7) * 256 + (bid >> 3);   // XCD swizzle
  const int bh   = orig >> 6;
  const int qblk = orig & 63;
  const int b    = bh >> 4, h = bh & 15;
  const int q0   = qblk * 32;

  const unsigned short* Kg0 = Kb + (size_t)(b * SEQ) * D_MODEL + h * 64;
  const unsigned short* Qg0 = Qb + (size_t)(b * SEQ + q0) * D_MODEL + h * 64;
  const unsigned short* Vg0 = Vt + (size_t)(bh * 64) * SEQ;
  const int* mrow = mask + b * SEQ;

  const int srow = tid >> 3, sch = tid & 7;
  const int ssw  = srow & 7;

  auto stageK = [&](int t) {
    const char* src = (const char*)(Kg0 + (size_t)(t * 64 + srow) * D_MODEL)
                      + ((sch ^ ssw) << 4);
    load16(src, Kbuf + ((t & 3) << 13) + (wid << 10));
  };
  auto stageV = [&](int t) {
    const char* src = (const char*)(Vg0 + (size_t)srow * SEQ + t * 64)
                      + ((sch ^ ssw) << 4);
    load16(src, Vbuf + ((t & 3) << 13) + (wid << 10));
  };

  // per-lane mask bits for t = i*64 + wt*16 + r16
  const int tb = wt * 16 + r16;
  unsigned mbits = 0;
  #pragma unroll 4
  for (int i = 0; i < 32; ++i)
    mbits |= (mrow[i * 64 + tb] ? 1u : 0u) << i;

  // ---- prologue: Q + K tiles 0..2 ---------------------------------------
  if (tid < 256) {
    const char* qsrc = (const char*)(Qg0 + (size_t)srow * D_MODEL)
                       + ((sch ^ ssw) << 4);
    load16(qsrc, Pt + (wid << 10));
  }
  stageK(0); stageK(1); stageK(2);
  __syncthreads();

  bf16x8 qa0, qa1;
  {
    const int row = qh * 16 + r16;
    const int sw = (row & 7) << 4;
    qa0 = *(const bf16x8*)(Pt + row * 128 + ((g * 16) ^ sw));
    qa1 = *(const bf16x8*)(Pt + row * 128 + ((g * 16 + 64) ^ sw));
  }

  const int krow = wt * 16 + r16;
  const int ksw  = (krow & 7) << 4;

  // ---- pass 1: rowsums ---------------------------------------------------
  float rs0 = 0.f, rs1 = 0.f, rs2 = 0.f, rs3 = 0.f;
  for (int i = 0; i < 32; ++i) {
    if (i < 30)
      asm volatile("s_waitcnt vmcnt(2)\n\ts_barrier" ::: "memory");
    else if (i == 30)
      asm volatile("s_waitcnt vmcnt(1)\n\ts_barrier" ::: "memory");
    else
      asm volatile("s_waitcnt vmcnt(0)\n\ts_barrier" ::: "memory");
    if (i + 3 < 32) stageK(i + 3);
    const char* Kt = Kbuf + ((i & 3) << 13);
    const bf16x8 kb0 = *(const bf16x8*)(Kt + krow * 128 + ((g * 16) ^ ksw));
    const bf16x8 kb1 = *(const bf16x8*)(Kt + krow * 128 + ((g * 16 + 64) ^ ksw));
    f32x4 c = {0.f, 0.f, 0.f, 0.f};
    __builtin_amdgcn_s_setprio(1);
    c = __builtin_amdgcn_mfma_f32_16x16x32_bf16(qa0, kb0, c, 0, 0, 0);
    c = __builtin_amdgcn_mfma_f32_16x16x32_bf16(qa1, kb1, c, 0, 0, 0);
    __builtin_amdgcn_s_setprio(0);
    if (!((mbits >> i) & 1u)) {
      rs0 += __expf(c[0]); rs1 += __expf(c[1]);
      rs2 += __expf(c[2]); rs3 += __expf(c[3]);
    }
  }

  // ---- rowsum reduction --------------------------------------------------
  rs0 += __shfl_xor(rs0, 1); rs0 += __shfl_xor(rs0, 2);
  rs0 += __shfl_xor(rs0, 4); rs0 += __shfl_xor(rs0, 8);
  rs1 += __shfl_xor(rs1, 1); rs1 += __shfl_xor(rs1, 2);
  rs1 += __shfl_xor(rs1, 4); rs1 += __shfl_xor(rs1, 8);
  rs2 += __shfl_xor(rs2, 1); rs2 += __shfl_xor(rs2, 2);
  rs2 += __shfl_xor(rs2, 4); rs2 += __shfl_xor(rs2, 8);
  rs3 += __shfl_xor(rs3, 1); rs3 += __shfl_xor(rs3, 2);
  rs3 += __shfl_xor(rs3, 4); rs3 += __shfl_xor(rs3, 8);
  if (r16 == 0) {
    red[wid * 16 + g * 4 + 0] = rs0;
    red[wid * 16 + g * 4 + 1] = rs1;
    red[wid * 16 + g * 4 + 2] = rs2;
    red[wid * 16 + g * 4 + 3] = rs3;
  }
  __syncthreads();

  float inv[4];
  #pragma unroll
  for (int j = 0; j < 4; ++j) {
    const int qt = g * 4 + j;
    inv[j] = 1.f / (red[(qh * 4 + 0) * 16 + qt] + red[(qh * 4 + 1) * 16 + qt] +
                    red[(qh * 4 + 2) * 16 + qt] + red[(qh * 4 + 3) * 16 + qt]);
  }

  // ---- pass 2 prologue ---------------------------------------------------
  stageK(0); stageV(0); stageK(1); stageV(1); stageK(2); stageV(2);
  __syncthreads();

  f32x4 oacc = {0.f, 0.f, 0.f, 0.f};
  const int prow0 = qh * 16 + g * 4;
  const int parow = qh * 16 + r16;
  const int pasw  = (parow & 7) << 4;
  // readback mapping: thread -> (q = tid>>4, 4 cols at (tid&15)*4)
  const int rbq  = tid >> 4, rbc = (tid & 15) * 4;
  const int rboff = (rbq * 128 + rbc * 2) ^ ((rbq & 7) << 4);
  float* const aT = attn + ((size_t)bh * SEQ + q0 + rbq) * SEQ + rbc;

  for (int i = 0; i < 32; ++i) {
    // FIFO newer than needed V(i-3) load: S+G2+S+G2+S = 7 steady
    if (i < 30)
      asm volatile("s_waitcnt vmcnt(7)\n\ts_barrier" ::: "memory");
    else if (i == 30)
      asm volatile("s_waitcnt vmcnt(5)\n\ts_barrier" ::: "memory");
    else
      asm volatile("s_waitcnt vmcnt(3)\n\ts_barrier" ::: "memory");
    if (i + 3 < 32) { stageK(i + 3); stageV(i + 3); }

    const char* Kt = Kbuf + ((i & 3) << 13);
    const bf16x8 kb0 = *(const bf16x8*)(Kt + krow * 128 + ((g * 16) ^ ksw));
    const bf16x8 kb1 = *(const bf16x8*)(Kt + krow * 128 + ((g * 16 + 64) ^ ksw));
    f32x4 c = {0.f, 0.f, 0.f, 0.f};
    __builtin_amdgcn_s_setprio(1);
    c = __builtin_amdgcn_mfma_f32_16x16x32_bf16(qa0, kb0, c, 0, 0, 0);
    c = __builtin_amdgcn_mfma_f32_16x16x32_bf16(qa1, kb1, c, 0, 0, 0);
    __builtin_amdgcn_s_setprio(0);

    const unsigned mk = (mbits >> i) & 1u;
    const float p0 = mk ? 0.f : __expf(c[0]) * inv[0];
    const float p1 = mk ? 0.f : __expf(c[1]) * inv[1];
    const float p2 = mk ? 0.f : __expf(c[2]) * inv[2];
    const float p3 = mk ? 0.f : __expf(c[3]) * inv[3];

    // P tile (bf16, XOR-swizzled rows)
    *(unsigned short*)(Pt + (((prow0 + 0) * 128 + tb * 2) ^ (((prow0 + 0) & 7) << 4))) = f2bf(p0);
    *(unsigned short*)(Pt + (((prow0 + 1) * 128 + tb * 2) ^ (((prow0 + 1) & 7) << 4))) = f2bf(p1);
    *(unsigned short*)(Pt + (((prow0 + 2) * 128 + tb * 2) ^ (((prow0 + 2) & 7) << 4))) = f2bf(p2);
    *(unsigned short*)(Pt + (((prow0 + 3) * 128 + tb * 2) ^ (((prow0 + 3) & 7) << 4))) = f2bf(p3);

    asm volatile("s_waitcnt lgkmcnt(0)\n\ts_barrier" ::: "memory");

    const char* Vtl = Vbuf + ((i & 3) << 13);
    const bf16x8 pa0 = *(const bf16x8*)(Pt + parow * 128 + ((g * 16) ^ pasw));
    const bf16x8 pa1 = *(const bf16x8*)(Pt + parow * 128 + ((g * 16 + 64) ^ pasw));
    const bf16x8 vb0 = *(const bf16x8*)(Vtl + krow * 128 + ((g * 16) ^ ksw));
    const bf16x8 vb1 = *(const bf16x8*)(Vtl + krow * 128 + ((g * 16 + 64) ^ ksw));
    __builtin_amdgcn_s_setprio(1);
    oacc = __builtin_amdgcn_mfma_f32_16x16x32_bf16(pa0, vb0, oacc, 0, 0, 0);
    oacc = __builtin_amdgcn_mfma_f32_16x16x32_bf16(pa1, vb1, oacc, 0, 0, 0);
    __builtin_amdgcn_s_setprio(0);

    // coalesced attn write: readback P tile, one float4 store per thread
    {
      const ushort4 pv = *(const ushort4*)(Pt + rboff);
      float4 o;
      o.x = bf2f(pv.x); o.y = bf2f(pv.y);
      o.z = bf2f(pv.z); o.w = bf2f(pv.w);
      *(float4*)(aT + i * 64) = o;
    }
  }

  // ---- O epilogue (already normalized), bf16 hi/lo -----------------------
  #pragma unroll
  for (int rr = 0; rr < 4; ++rr) {
    const size_t idx = (size_t)(b * SEQ + q0 + qh * 16 + g * 4 + rr) * D_MODEL
                       + h * 64 + wt * 16 + r16;
    const float o = oacc[rr];
    const unsigned short ohv = f2bf(o);
    Oh[idx] = ohv;
    Ol[idx] = f2bf(o - bf2f(ohv));
  }
}

// ---------------------------------------------------------------------------
extern "C" void kernel_launch(void* const* d_in, const int* in_sizes, int n_in,
                              void* d_out, int out_size, void* d_ws, size_t ws_size,
                              hipStream_t stream) {
  const float* v    = (const float*)d_in[0];
  const float* k    = (const float*)d_in[1];
  const float* q    = (const float*)d_in[2];
  const int*   mask = (const int*)  d_in[3];
  const float* Wq   = (const float*)d_in[4];
  const float* bq   = (const float*)d_in[5];
  const float* Wk   = (const float*)d_in[6];
  const float* bk   = (const float*)d_in[7];
  const float* Wv   = (const float*)d_in[8];
  const float* bv   = (const float*)d_in[9];
  const float* Wo   = (const float*)d_in[10];
  const float* bo   = (const float*)d_in[11];

  const size_t NTOK = (size_t)2 * SEQ;            // 4096 tokens
  const size_t TOKF = NTOK * D_MODEL;             // 4,194,304 elements
  const size_t WSZ  = (size_t)D_MODEL * D_MODEL;  // 1,048,576
  float* out  = (float*)d_out;
  float* attn = out + TOKF;

  unsigned short* qx   = (unsigned short*)d_ws;   // bf16 inputs
  unsigned short* kx   = qx + TOKF;
  unsigned short* vx   = kx + TOKF;
  unsigned short* Qbf  = vx + TOKF;               // projections
  unsigned short* Kbf  = Qbf + TOKF;
  unsigned short* Vtb  = Kbf + TOKF;
  unsigned short* Ohb  = Vtb + TOKF;              // attn O hi/lo
  unsigned short* Olb  = Ohb + TOKF;
  unsigned short* Wqt  = Olb + TOKF;              // transposed bf16 weights
  unsigned short* Wkt  = Wqt + WSZ;
  unsigned short* Wvt  = Wkt + WSZ;
  unsigned short* Woth = Wvt + WSZ;
  unsigned short* Wotl = Woth + WSZ;

  const int cvtg = (int)(TOKF / 4 / 256);         // 4096 blocks
  cvt_bf16<<<cvtg, 256, 0, stream>>>((const float4*)q, (ushort4*)qx);
  cvt_bf16<<<cvtg, 256, 0, stream>>>((const float4*)k, (ushort4*)kx);
  cvt_bf16<<<cvtg, 256, 0, stream>>>((const float4*)v, (ushort4*)vx);
  const dim3 wg(16, 16);
  wt_cvt<false><<<wg, 256, 0, stream>>>(Wq, Wqt, nullptr);
  wt_cvt<false><<<wg, 256, 0, stream>>>(Wk, Wkt, nullptr);
  wt_cvt<false><<<wg, 256, 0, stream>>>(Wv, Wvt, nullptr);
  wt_cvt<true> <<<wg, 256, 0, stream>>>(Wo, Woth, Wotl);

  gemm128<0><<<512, 512, 0, stream>>>(qx, Wqt, bq, Qbf, 0.125f);
  gemm128<0><<<512, 512, 0, stream>>>(kx, Wkt, bk, Kbf, 1.0f);
  gemm128<1><<<512, 512, 0, stream>>>(vx, Wvt, bv, Vtb, 1.0f);

  attn_2pass<<<2048, 512, 0, stream>>>(Qbf, Kbf, Vtb, mask, attn, Ohb, Olb);

  gemm64s<<<1024, 256, 0, stream>>>(Ohb, Olb, Woth, Wotl, bo, out);
}

// Round 6
// 300.653 us; speedup vs baseline: 11.6799x; 1.1014x over previous
//
#include <hip/hip_runtime.h>
#include <hip/hip_bf16.h>
#include <math.h>

#define D_MODEL 1024
#define SEQ     2048
#define NHEAD   16

typedef __attribute__((ext_vector_type(8))) short bf16x8;
typedef __attribute__((ext_vector_type(8))) unsigned short u16x8;
typedef __attribute__((ext_vector_type(4))) float f32x4;
typedef const __attribute__((address_space(1))) unsigned int* gas_u32p;
typedef __attribute__((address_space(3))) unsigned int* las_u32p;

__device__ __forceinline__ void load16(const void* g, void* l) {
  __builtin_amdgcn_global_load_lds((gas_u32p)g, (las_u32p)l, 16, 0, 0);
}

__device__ __forceinline__ unsigned short f2bf(float f) {
  __hip_bfloat16 h = __float2bfloat16(f);
  return *(unsigned short*)&h;
}
__device__ __forceinline__ float bf2f(unsigned short u) {
  return __uint_as_float((unsigned)u << 16);
}

// ---------------------------------------------------------------------------
// fp32 -> bf16 elementwise (float4 -> ushort4)
// ---------------------------------------------------------------------------
__global__ __launch_bounds__(256) void cvt_bf16(
    const float4* __restrict__ in, ushort4* __restrict__ out) {
  const int i = blockIdx.x * 256 + threadIdx.x;
  const float4 f = in[i];
  ushort4 u;
  u.x = f2bf(f.x); u.y = f2bf(f.y); u.z = f2bf(f.z); u.w = f2bf(f.w);
  out[i] = u;
}

// ---------------------------------------------------------------------------
// W [1024 k][1024 n] fp32 -> Wt bf16 [n][k]
// ---------------------------------------------------------------------------
__global__ __launch_bounds__(256) void wt_cvt(
    const float* __restrict__ W, unsigned short* __restrict__ Wh) {
  __shared__ float t[64][65];
  const int tid = threadIdx.x;
  const int k0 = blockIdx.y * 64, n0 = blockIdx.x * 64;
  #pragma unroll
  for (int it = 0; it < 4; ++it) {
    const int r = it * 16 + (tid >> 4), c4 = (tid & 15) * 4;
    const float4 f = *(const float4*)&W[(size_t)(k0 + r) * D_MODEL + n0 + c4];
    t[r][c4 + 0] = f.x; t[r][c4 + 1] = f.y;
    t[r][c4 + 2] = f.z; t[r][c4 + 3] = f.w;
  }
  __syncthreads();
  #pragma unroll
  for (int it = 0; it < 4; ++it) {
    const int n = it * 16 + (tid >> 4), k4 = (tid & 15) * 4;
    ushort4 uh;
    uh.x = f2bf(t[k4 + 0][n]); uh.y = f2bf(t[k4 + 1][n]);
    uh.z = f2bf(t[k4 + 2][n]); uh.w = f2bf(t[k4 + 3][n]);
    *(ushort4*)&Wh[(size_t)(n0 + n) * D_MODEL + k0 + k4] = uh;
  }
}

// ---------------------------------------------------------------------------
// Fused Q/K/V projections. 128x64 tile, BK=64, 512 threads (8 waves 4x2).
// grid 1536 = 3 x 512; per-block operand select. which==2 writes per-head-
// transposed Vt; which==0 scales by 0.125 (Q pre-scale).
// ---------------------------------------------------------------------------
__global__ __launch_bounds__(512, 4) void gemm128_qkv(
    const unsigned short* __restrict__ qx, const unsigned short* __restrict__ kx,
    const unsigned short* __restrict__ vx,
    const unsigned short* __restrict__ Wqt, const unsigned short* __restrict__ Wkt,
    const unsigned short* __restrict__ Wvt,
    const float* __restrict__ bq, const float* __restrict__ bk,
    const float* __restrict__ bv,
    unsigned short* __restrict__ Qo, unsigned short* __restrict__ Ko,
    unsigned short* __restrict__ Vto) {
  __shared__ char lds[49152];                 // 2 x (16K A + 8K B)
  const int tid = threadIdx.x;
  const int lane = tid & 63, wid = tid >> 6;
  const int r16 = lane & 15, g = lane >> 4;
  const int bid = blockIdx.x;
  const int orig = (bid & 7) * 192 + (bid >> 3);  // XCD swizzle (1536%8==0)
  const int which = orig >> 9;                    // 0:Q 1:K 2:V
  const int sub = orig & 511;
  const int bm = sub >> 4, bn = sub & 15;
  const int row0 = bm * 128, col0 = bn * 64;
  const int wm = wid >> 1, wn = wid & 1;

  const unsigned short* A = (which == 0) ? qx : (which == 1) ? kx : vx;
  const unsigned short* W = (which == 0) ? Wqt : (which == 1) ? Wkt : Wvt;
  const float* bias = (which == 0) ? bq : (which == 1) ? bk : bv;

  const unsigned short* Ag = A + (size_t)row0 * D_MODEL;
  const unsigned short* Bg = W + (size_t)col0 * D_MODEL;

  auto stage = [&](int buf, int k0) {
    char* base = lds + buf * 24576;
    #pragma unroll
    for (int c = 0; c < 2; ++c) {             // A: 128 rows x 64 k
      const int idx = c * 512 + tid;
      const int r = idx >> 3, ch = idx & 7;
      load16(Ag + (size_t)r * D_MODEL + k0 + ((ch ^ (r & 7)) << 3),
             base + idx * 16);
    }
    {                                          // B: 64 rows x 64 k
      const int r = tid >> 3, ch = tid & 7;
      load16(Bg + (size_t)r * D_MODEL + k0 + ((ch ^ (r & 7)) << 3),
             base + 16384 + tid * 16);
    }
  };

  stage(0, 0);
  f32x4 acc[2][2] = {};

  for (int s = 0; s < 16; ++s) {
    __syncthreads();
    if (s < 15) stage((s + 1) & 1, (s + 1) * 64);
    const char* base = lds + (s & 1) * 24576;
    #pragma unroll
    for (int kk = 0; kk < 2; ++kk) {
      bf16x8 a[2], b[2];
      #pragma unroll
      for (int mi = 0; mi < 2; ++mi) {
        const int r = wm * 32 + mi * 16 + r16;
        a[mi] = *(const bf16x8*)(base + r * 128 + (((g + kk * 4) ^ (r & 7)) << 4));
      }
      #pragma unroll
      for (int ni = 0; ni < 2; ++ni) {
        const int r = wn * 32 + ni * 16 + r16;
        b[ni] = *(const bf16x8*)(base + 16384 + r * 128 +
                                 (((g + kk * 4) ^ (r & 7)) << 4));
      }
      #pragma unroll
      for (int mi = 0; mi < 2; ++mi)
        #pragma unroll
        for (int ni = 0; ni < 2; ++ni)
          acc[mi][ni] = __builtin_amdgcn_mfma_f32_16x16x32_bf16(
              a[mi], b[ni], acc[mi][ni], 0, 0, 0);
    }
  }

  if (which < 2) {
    unsigned short* C = (which == 0) ? Qo : Ko;
    const float scale = (which == 0) ? 0.125f : 1.0f;
    #pragma unroll
    for (int mi = 0; mi < 2; ++mi)
      #pragma unroll
      for (int ni = 0; ni < 2; ++ni) {
        const int col = col0 + wn * 32 + ni * 16 + r16;
        const float bb = bias[col];
        const int rowb = row0 + wm * 32 + mi * 16 + g * 4;
        #pragma unroll
        for (int j = 0; j < 4; ++j)
          C[(size_t)(rowb + j) * D_MODEL + col] =
              f2bf((acc[mi][ni][j] + bb) * scale);
      }
  } else {
    #pragma unroll
    for (int mi = 0; mi < 2; ++mi)
      #pragma unroll
      for (int ni = 0; ni < 2; ++ni) {
        const int col = col0 + wn * 32 + ni * 16 + r16;
        const int hh = col >> 6, dd = col & 63;
        const float bb = bias[col];
        const int rowb = row0 + wm * 32 + mi * 16 + g * 4;
        const int b_ = rowb >> 11, tt = rowb & 2047;
        ushort4 u;
        u.x = f2bf(acc[mi][ni][0] + bb);
        u.y = f2bf(acc[mi][ni][1] + bb);
        u.z = f2bf(acc[mi][ni][2] + bb);
        u.w = f2bf(acc[mi][ni][3] + bb);
        *(ushort4*)&Vto[((size_t)((b_ * NHEAD + hh) * 64 + dd)) * SEQ + tt] = u;
      }
  }
}

// ---------------------------------------------------------------------------
// Final GEMM: out = (Oh + Ol) @ Wh + bias, fp32 out. 128x64 tile, 2-term
// split precision (Oh*Wh + Ol*Wh). LDS 2 x 40960 = 80K -> 2 blocks/CU.
// ---------------------------------------------------------------------------
__global__ __launch_bounds__(512, 4) void gemm128s(
    const unsigned short* __restrict__ A, const unsigned short* __restrict__ Al,
    const unsigned short* __restrict__ B, const float* __restrict__ bias,
    float* __restrict__ O) {
  __shared__ char lds[81920];
  const int tid = threadIdx.x;
  const int lane = tid & 63, wid = tid >> 6;
  const int r16 = lane & 15, g = lane >> 4;
  const int bid = blockIdx.x;
  const int orig = (bid & 7) * 64 + (bid >> 3);   // XCD swizzle (512%8==0)
  const int bm = orig >> 4, bn = orig & 15;
  const int row0 = bm * 128, col0 = bn * 64;
  const int wm = wid >> 1, wn = wid & 1;

  const unsigned short* Ag  = A  + (size_t)row0 * D_MODEL;
  const unsigned short* Alg = Al + (size_t)row0 * D_MODEL;
  const unsigned short* Bg  = B  + (size_t)col0 * D_MODEL;

  auto stage = [&](int buf, int k0) {
    char* base = lds + buf * 40960;
    #pragma unroll
    for (int c = 0; c < 2; ++c) {
      const int idx = c * 512 + tid;
      const int r = idx >> 3, ch = idx & 7;
      const size_t off = (size_t)r * D_MODEL + k0 + ((ch ^ (r & 7)) << 3);
      load16(Ag + off, base + idx * 16);
      load16(Alg + off, base + 16384 + idx * 16);
    }
    {
      const int r = tid >> 3, ch = tid & 7;
      load16(Bg + (size_t)r * D_MODEL + k0 + ((ch ^ (r & 7)) << 3),
             base + 32768 + tid * 16);
    }
  };

  stage(0, 0);
  f32x4 acc[2][2] = {};

  for (int s = 0; s < 16; ++s) {
    __syncthreads();
    if (s < 15) stage((s + 1) & 1, (s + 1) * 64);
    const char* base = lds + (s & 1) * 40960;
    #pragma unroll
    for (int kk = 0; kk < 2; ++kk) {
      bf16x8 a[2], al[2], b[2];
      #pragma unroll
      for (int mi = 0; mi < 2; ++mi) {
        const int r = wm * 32 + mi * 16 + r16;
        const int off = r * 128 + (((g + kk * 4) ^ (r & 7)) << 4);
        a[mi]  = *(const bf16x8*)(base + off);
        al[mi] = *(const bf16x8*)(base + 16384 + off);
      }
      #pragma unroll
      for (int ni = 0; ni < 2; ++ni) {
        const int r = wn * 32 + ni * 16 + r16;
        b[ni] = *(const bf16x8*)(base + 32768 + r * 128 +
                                 (((g + kk * 4) ^ (r & 7)) << 4));
      }
      #pragma unroll
      for (int mi = 0; mi < 2; ++mi)
        #pragma unroll
        for (int ni = 0; ni < 2; ++ni) {
          acc[mi][ni] = __builtin_amdgcn_mfma_f32_16x16x32_bf16(
              a[mi], b[ni], acc[mi][ni], 0, 0, 0);
          acc[mi][ni] = __builtin_amdgcn_mfma_f32_16x16x32_bf16(
              al[mi], b[ni], acc[mi][ni], 0, 0, 0);
        }
    }
  }

  #pragma unroll
  for (int mi = 0; mi < 2; ++mi)
    #pragma unroll
    for (int ni = 0; ni < 2; ++ni) {
      const int col = col0 + wn * 32 + ni * 16 + r16;
      const float bb = bias[col];
      const int rowb = row0 + wm * 32 + mi * 16 + g * 4;
      #pragma unroll
      for (int j = 0; j < 4; ++j)
        O[(size_t)(rowb + j) * D_MODEL + col] = acc[mi][ni][j] + bb;
    }
}

// ---------------------------------------------------------------------------
// Two-pass MFMA attention, QB=64. Block = (b,h, 64 q-rows), 512 threads.
// Wave (wq2,wt): 2 q-frags (wq2*32+{0,16}) x 1 t/d-window (wt*16).
// Pass 1: stream K (ring-4, 1 load16/tile/thread), QK^T -> exp -> rowsums.
// Pass 2: stream K+V, QK^T -> normalized bf16 P[64][64] in LDS -> PV MFMA,
//         attn via coalesced LDS readback (u16x8 -> 2 float4 stores).
// vmcnt: pass1 2/1/0; pass2 4,6,8,10..10,8,6 (2 loads + 2 stores per iter).
// LDS 74752 -> 2 blocks/CU.
// ---------------------------------------------------------------------------
__global__ __launch_bounds__(512, 4) void attn_2pass(
    const unsigned short* __restrict__ Qb,   // bf16 [4096][1024], pre-scaled /8
    const unsigned short* __restrict__ Kb,   // bf16 [4096][1024]
    const unsigned short* __restrict__ Vt,   // bf16 [32*64][2048]
    const int* __restrict__ mask,            // [2][2048]
    float* __restrict__ attn,                // [32][2048][2048]
    unsigned short* __restrict__ Oh,         // bf16 hi [4096][1024]
    unsigned short* __restrict__ Ol) {       // bf16 lo [4096][1024]
  __shared__ char lds[74752];
  char* const Kbuf = lds;                    // 4 x 8192
  char* const Vbuf = lds + 32768;            // 4 x 8192 (slot0 = Q staging)
  char* const Pt   = lds + 65536;            // 8192: P tile 64x64 bf16
  float* const red = (float*)(lds + 73728);  // [4 wt][64 q]

  const int tid  = threadIdx.x;
  const int lane = tid & 63;
  const int wid  = tid >> 6;
  const int r16  = lane & 15;
  const int g    = lane >> 4;
  const int wq2  = wid >> 2;
  const int wt   = wid & 3;

  const int bid  = blockIdx.x;
  const int orig = (bid & 7) * 128 + (bid >> 3);   // XCD swizzle (1024%8==0)
  const int bh   = orig >> 5;
  const int qblk = orig & 31;
  const int b    = bh >> 4, h = bh & 15;
  const int q0   = qblk * 64;

  const unsigned short* Kg0 = Kb + (size_t)(b * SEQ) * D_MODEL + h * 64;
  const unsigned short* Qg0 = Qb + (size_t)(b * SEQ + q0) * D_MODEL + h * 64;
  const unsigned short* Vg0 = Vt + (size_t)(bh * 64) * SEQ;
  const int* mrow = mask + b * SEQ;

  const int srow = tid >> 3, sch = tid & 7;
  const int ssw  = srow & 7;

  auto stageK = [&](int t) {
    load16((const char*)(Kg0 + (size_t)(t * 64 + srow) * D_MODEL) +
               ((sch ^ ssw) << 4),
           Kbuf + ((t & 3) << 13) + tid * 16);
  };
  auto stageV = [&](int t) {
    load16((const char*)(Vg0 + (size_t)srow * SEQ + t * 64) +
               ((sch ^ ssw) << 4),
           Vbuf + ((t & 3) << 13) + tid * 16);
  };

  // per-lane mask bits for t = i*64 + wt*16 + r16 (consumed before staging)
  const int tb = wt * 16 + r16;
  unsigned mbits = 0;
  #pragma unroll 4
  for (int i = 0; i < 32; ++i)
    mbits |= (mrow[i * 64 + tb] ? 1u : 0u) << i;
  asm volatile("s_waitcnt vmcnt(0)" ::: "memory");  // clean FIFO before staging

  // ---- prologue: Q into Vbuf slot0, K tiles 0..2 -------------------------
  load16((const char*)(Qg0 + (size_t)srow * D_MODEL) + ((sch ^ ssw) << 4),
         Vbuf + tid * 16);
  stageK(0); stageK(1); stageK(2);
  asm volatile("s_waitcnt vmcnt(3)\n\ts_barrier" ::: "memory");  // Q resident

  bf16x8 qa[2][2];
  #pragma unroll
  for (int f = 0; f < 2; ++f) {
    const int row = wq2 * 32 + f * 16 + r16;
    const int sw = (row & 7) << 4;
    qa[f][0] = *(const bf16x8*)(Vbuf + row * 128 + ((g * 16) ^ sw));
    qa[f][1] = *(const bf16x8*)(Vbuf + row * 128 + ((g * 16 + 64) ^ sw));
  }

  const int krow = wt * 16 + r16;
  const int ksw  = (krow & 7) << 4;

  // ---- pass 1: rowsums ---------------------------------------------------
  float rs[2][4] = {};
  for (int i = 0; i < 32; ++i) {
    if (i < 30)
      asm volatile("s_waitcnt vmcnt(2)\n\ts_barrier" ::: "memory");
    else if (i == 30)
      asm volatile("s_waitcnt vmcnt(1)\n\ts_barrier" ::: "memory");
    else
      asm volatile("s_waitcnt vmcnt(0)\n\ts_barrier" ::: "memory");
    if (i + 3 < 32) stageK(i + 3);
    const char* Kt = Kbuf + ((i & 3) << 13);
    const bf16x8 kb0 = *(const bf16x8*)(Kt + krow * 128 + ((g * 16) ^ ksw));
    const bf16x8 kb1 = *(const bf16x8*)(Kt + krow * 128 + ((g * 16 + 64) ^ ksw));
    f32x4 c0 = {0.f, 0.f, 0.f, 0.f}, c1 = {0.f, 0.f, 0.f, 0.f};
    __builtin_amdgcn_s_setprio(1);
    c0 = __builtin_amdgcn_mfma_f32_16x16x32_bf16(qa[0][0], kb0, c0, 0, 0, 0);
    c0 = __builtin_amdgcn_mfma_f32_16x16x32_bf16(qa[0][1], kb1, c0, 0, 0, 0);
    c1 = __builtin_amdgcn_mfma_f32_16x16x32_bf16(qa[1][0], kb0, c1, 0, 0, 0);
    c1 = __builtin_amdgcn_mfma_f32_16x16x32_bf16(qa[1][1], kb1, c1, 0, 0, 0);
    __builtin_amdgcn_s_setprio(0);
    if (!((mbits >> i) & 1u)) {
      rs[0][0] += __expf(c0[0]); rs[0][1] += __expf(c0[1]);
      rs[0][2] += __expf(c0[2]); rs[0][3] += __expf(c0[3]);
      rs[1][0] += __expf(c1[0]); rs[1][1] += __expf(c1[1]);
      rs[1][2] += __expf(c1[2]); rs[1][3] += __expf(c1[3]);
    }
  }

  // ---- rowsum reduction (16-lane groups share a q-frag row set) ----------
  #pragma unroll
  for (int f = 0; f < 2; ++f)
    #pragma unroll
    for (int j = 0; j < 4; ++j) {
      float v = rs[f][j];
      v += __shfl_xor(v, 1); v += __shfl_xor(v, 2);
      v += __shfl_xor(v, 4); v += __shfl_xor(v, 8);
      rs[f][j] = v;
    }
  if (r16 == 0) {
    #pragma unroll
    for (int f = 0; f < 2; ++f)
      #pragma unroll
      for (int j = 0; j < 4; ++j)
        red[wt * 64 + wq2 * 32 + f * 16 + g * 4 + j] = rs[f][j];
  }
  __syncthreads();

  float inv_[2][4];
  #pragma unroll
  for (int f = 0; f < 2; ++f)
    #pragma unroll
    for (int j = 0; j < 4; ++j) {
      const int row = wq2 * 32 + f * 16 + g * 4 + j;
      inv_[f][j] = 1.f / (red[0 * 64 + row] + red[1 * 64 + row] +
                          red[2 * 64 + row] + red[3 * 64 + row]);
    }

  // ---- pass 2 prologue ---------------------------------------------------
  stageK(0); stageV(0); stageK(1); stageV(1); stageK(2); stageV(2);

  f32x4 o0 = {0.f, 0.f, 0.f, 0.f}, o1 = {0.f, 0.f, 0.f, 0.f};
  // readback mapping: thread -> q row tid>>3, 8 cols at (tid&7)*8
  const int rbq = tid >> 3, rbc8 = (tid & 7) * 8;
  const int rboff = (rbq * 128 + rbc8 * 2) ^ ((rbq & 7) << 4);
  float* const aT = attn + ((size_t)bh * SEQ + q0 + rbq) * SEQ + rbc8;

  for (int i = 0; i < 32; ++i) {
    // FIFO (2 loads + 2 stores/iter, 3-deep prefetch): 4,6,8,10..10,8,6
    if (i >= 3 && i <= 29)
      asm volatile("s_waitcnt vmcnt(10)\n\ts_barrier" ::: "memory");
    else if (i == 2 || i == 30)
      asm volatile("s_waitcnt vmcnt(8)\n\ts_barrier" ::: "memory");
    else if (i == 1 || i == 31)
      asm volatile("s_waitcnt vmcnt(6)\n\ts_barrier" ::: "memory");
    else
      asm volatile("s_waitcnt vmcnt(4)\n\ts_barrier" ::: "memory");
    if (i + 3 < 32) { stageK(i + 3); stageV(i + 3); }

    const char* Kt = Kbuf + ((i & 3) << 13);
    const bf16x8 kb0 = *(const bf16x8*)(Kt + krow * 128 + ((g * 16) ^ ksw));
    const bf16x8 kb1 = *(const bf16x8*)(Kt + krow * 128 + ((g * 16 + 64) ^ ksw));
    f32x4 c0 = {0.f, 0.f, 0.f, 0.f}, c1 = {0.f, 0.f, 0.f, 0.f};
    __builtin_amdgcn_s_setprio(1);
    c0 = __builtin_amdgcn_mfma_f32_16x16x32_bf16(qa[0][0], kb0, c0, 0, 0, 0);
    c0 = __builtin_amdgcn_mfma_f32_16x16x32_bf16(qa[0][1], kb1, c0, 0, 0, 0);
    c1 = __builtin_amdgcn_mfma_f32_16x16x32_bf16(qa[1][0], kb0, c1, 0, 0, 0);
    c1 = __builtin_amdgcn_mfma_f32_16x16x32_bf16(qa[1][1], kb1, c1, 0, 0, 0);
    __builtin_amdgcn_s_setprio(0);

    const unsigned mk = (mbits >> i) & 1u;
    float p[2][4];
    p[0][0] = mk ? 0.f : __expf(c0[0]) * inv_[0][0];
    p[0][1] = mk ? 0.f : __expf(c0[1]) * inv_[0][1];
    p[0][2] = mk ? 0.f : __expf(c0[2]) * inv_[0][2];
    p[0][3] = mk ? 0.f : __expf(c0[3]) * inv_[0][3];
    p[1][0] = mk ? 0.f : __expf(c1[0]) * inv_[1][0];
    p[1][1] = mk ? 0.f : __expf(c1[1]) * inv_[1][1];
    p[1][2] = mk ? 0.f : __expf(c1[2]) * inv_[1][2];
    p[1][3] = mk ? 0.f : __expf(c1[3]) * inv_[1][3];

    #pragma unroll
    for (int f = 0; f < 2; ++f)
      #pragma unroll
      for (int j = 0; j < 4; ++j) {
        const int row = wq2 * 32 + f * 16 + g * 4 + j;
        *(unsigned short*)(Pt + ((row * 128 + tb * 2) ^ ((row & 7) << 4))) =
            f2bf(p[f][j]);
      }

    asm volatile("s_waitcnt lgkmcnt(0)\n\ts_barrier" ::: "memory");

    const char* Vtl = Vbuf + ((i & 3) << 13);
    const bf16x8 vb0 = *(const bf16x8*)(Vtl + krow * 128 + ((g * 16) ^ ksw));
    const bf16x8 vb1 = *(const bf16x8*)(Vtl + krow * 128 + ((g * 16 + 64) ^ ksw));
    {
      const int pr0 = wq2 * 32 + r16;
      const int psw0 = (pr0 & 7) << 4;
      const bf16x8 pa0 = *(const bf16x8*)(Pt + pr0 * 128 + ((g * 16) ^ psw0));
      const bf16x8 pa1 = *(const bf16x8*)(Pt + pr0 * 128 + ((g * 16 + 64) ^ psw0));
      const int pr1 = pr0 + 16;
      const int psw1 = (pr1 & 7) << 4;
      const bf16x8 pb0 = *(const bf16x8*)(Pt + pr1 * 128 + ((g * 16) ^ psw1));
      const bf16x8 pb1 = *(const bf16x8*)(Pt + pr1 * 128 + ((g * 16 + 64) ^ psw1));
      __builtin_amdgcn_s_setprio(1);
      o0 = __builtin_amdgcn_mfma_f32_16x16x32_bf16(pa0, vb0, o0, 0, 0, 0);
      o0 = __builtin_amdgcn_mfma_f32_16x16x32_bf16(pa1, vb1, o0, 0, 0, 0);
      o1 = __builtin_amdgcn_mfma_f32_16x16x32_bf16(pb0, vb0, o1, 0, 0, 0);
      o1 = __builtin_amdgcn_mfma_f32_16x16x32_bf16(pb1, vb1, o1, 0, 0, 0);
      __builtin_amdgcn_s_setprio(0);
    }

    // coalesced attn write: u16x8 LDS readback -> 2 float4 stores
    {
      const u16x8 pv = *(const u16x8*)(Pt + rboff);
      float4 oA, oB;
      oA.x = bf2f(pv[0]); oA.y = bf2f(pv[1]);
      oA.z = bf2f(pv[2]); oA.w = bf2f(pv[3]);
      oB.x = bf2f(pv[4]); oB.y = bf2f(pv[5]);
      oB.z = bf2f(pv[6]); oB.w = bf2f(pv[7]);
      *(float4*)(aT + (size_t)i * 64) = oA;
      *(float4*)(aT + (size_t)i * 64 + 4) = oB;
    }
  }

  // ---- O epilogue (already normalized), bf16 hi/lo -----------------------
  #pragma unroll
  for (int f = 0; f < 2; ++f)
    #pragma unroll
    for (int j = 0; j < 4; ++j) {
      const int row = q0 + wq2 * 32 + f * 16 + g * 4 + j;
      const size_t idx = (size_t)(b * SEQ + row) * D_MODEL + h * 64 + wt * 16 + r16;
      const float o = f ? o1[j] : o0[j];
      const unsigned short ohv = f2bf(o);
      Oh[idx] = ohv;
      Ol[idx] = f2bf(o - bf2f(ohv));
    }
}

// ---------------------------------------------------------------------------
extern "C" void kernel_launch(void* const* d_in, const int* in_sizes, int n_in,
                              void* d_out, int out_size, void* d_ws, size_t ws_size,
                              hipStream_t stream) {
  const float* v    = (const float*)d_in[0];
  const float* k    = (const float*)d_in[1];
  const float* q    = (const float*)d_in[2];
  const int*   mask = (const int*)  d_in[3];
  const float* Wq   = (const float*)d_in[4];
  const float* bq   = (const float*)d_in[5];
  const float* Wk   = (const float*)d_in[6];
  const float* bk   = (const float*)d_in[7];
  const float* Wv   = (const float*)d_in[8];
  const float* bv   = (const float*)d_in[9];
  const float* Wo   = (const float*)d_in[10];
  const float* bo   = (const float*)d_in[11];

  const size_t NTOK = (size_t)2 * SEQ;            // 4096 tokens
  const size_t TOKF = NTOK * D_MODEL;             // 4,194,304 elements
  const size_t WSZ  = (size_t)D_MODEL * D_MODEL;  // 1,048,576
  float* out  = (float*)d_out;
  float* attn = out + TOKF;

  unsigned short* qx   = (unsigned short*)d_ws;   // bf16 inputs
  unsigned short* kx   = qx + TOKF;
  unsigned short* vx   = kx + TOKF;
  unsigned short* Qbf  = vx + TOKF;               // projections
  unsigned short* Kbf  = Qbf + TOKF;
  unsigned short* Vtb  = Kbf + TOKF;
  unsigned short* Ohb  = Vtb + TOKF;              // attn O hi/lo
  unsigned short* Olb  = Ohb + TOKF;
  unsigned short* Wqt  = Olb + TOKF;              // transposed bf16 weights
  unsigned short* Wkt  = Wqt + WSZ;
  unsigned short* Wvt  = Wkt + WSZ;
  unsigned short* Woth = Wvt + WSZ;

  const int cvtg = (int)(TOKF / 4 / 256);         // 4096 blocks
  cvt_bf16<<<cvtg, 256, 0, stream>>>((const float4*)q, (ushort4*)qx);
  cvt_bf16<<<cvtg, 256, 0, stream>>>((const float4*)k, (ushort4*)kx);
  cvt_bf16<<<cvtg, 256, 0, stream>>>((const float4*)v, (ushort4*)vx);
  const dim3 wg(16, 16);
  wt_cvt<<<wg, 256, 0, stream>>>(Wq, Wqt);
  wt_cvt<<<wg, 256, 0, stream>>>(Wk, Wkt);
  wt_cvt<<<wg, 256, 0, stream>>>(Wv, Wvt);
  wt_cvt<<<wg, 256, 0, stream>>>(Wo, Woth);

  gemm128_qkv<<<1536, 512, 0, stream>>>(qx, kx, vx, Wqt, Wkt, Wvt,
                                        bq, bk, bv, Qbf, Kbf, Vtb);

  attn_2pass<<<1024, 512, 0, stream>>>(Qbf, Kbf, Vtb, mask, attn, Ohb, Olb);

  gemm128s<<<512, 512, 0, stream>>>(Ohb, Olb, Woth, bo, out);
}

// Round 7
// 283.190 us; speedup vs baseline: 12.4002x; 1.0617x over previous
//
#include <hip/hip_runtime.h>
#include <hip/hip_bf16.h>
#include <math.h>

#define D_MODEL 1024
#define SEQ     2048
#define NHEAD   16

typedef __attribute__((ext_vector_type(8))) short bf16x8;
typedef __attribute__((ext_vector_type(8))) unsigned short u16x8;
typedef __attribute__((ext_vector_type(4))) float f32x4;
typedef const __attribute__((address_space(1))) unsigned int* gas_u32p;
typedef __attribute__((address_space(3))) unsigned int* las_u32p;

__device__ __forceinline__ void load16(const void* g, void* l) {
  __builtin_amdgcn_global_load_lds((gas_u32p)g, (las_u32p)l, 16, 0, 0);
}

__device__ __forceinline__ unsigned short f2bf(float f) {
  __hip_bfloat16 h = __float2bfloat16(f);
  return *(unsigned short*)&h;
}
__device__ __forceinline__ float bf2f(unsigned short u) {
  return __uint_as_float((unsigned)u << 16);
}

// ---------------------------------------------------------------------------
// fp32 -> bf16 for q,k,v in one launch (blockIdx.y selects tensor)
// ---------------------------------------------------------------------------
__global__ __launch_bounds__(256) void cvt3_bf16(
    const float4* __restrict__ q, const float4* __restrict__ k,
    const float4* __restrict__ v, ushort4* __restrict__ qo,
    ushort4* __restrict__ ko, ushort4* __restrict__ vo) {
  const int i = blockIdx.x * 256 + threadIdx.x;
  const float4* in = (blockIdx.y == 0) ? q : (blockIdx.y == 1) ? k : v;
  ushort4* out = (blockIdx.y == 0) ? qo : (blockIdx.y == 1) ? ko : vo;
  const float4 f = in[i];
  ushort4 u;
  u.x = f2bf(f.x); u.y = f2bf(f.y); u.z = f2bf(f.z); u.w = f2bf(f.w);
  out[i] = u;
}

// ---------------------------------------------------------------------------
// 4 x (W [1024 k][1024 n] fp32 -> Wt bf16 [n][k]), blockIdx.z selects
// ---------------------------------------------------------------------------
__global__ __launch_bounds__(256) void wt_cvt4(
    const float* __restrict__ W0, const float* __restrict__ W1,
    const float* __restrict__ W2, const float* __restrict__ W3,
    unsigned short* __restrict__ O0, unsigned short* __restrict__ O1,
    unsigned short* __restrict__ O2, unsigned short* __restrict__ O3) {
  __shared__ float t[64][65];
  const int z = blockIdx.z;
  const float* W = (z == 0) ? W0 : (z == 1) ? W1 : (z == 2) ? W2 : W3;
  unsigned short* Wh = (z == 0) ? O0 : (z == 1) ? O1 : (z == 2) ? O2 : O3;
  const int tid = threadIdx.x;
  const int k0 = blockIdx.y * 64, n0 = blockIdx.x * 64;
  #pragma unroll
  for (int it = 0; it < 4; ++it) {
    const int r = it * 16 + (tid >> 4), c4 = (tid & 15) * 4;
    const float4 f = *(const float4*)&W[(size_t)(k0 + r) * D_MODEL + n0 + c4];
    t[r][c4 + 0] = f.x; t[r][c4 + 1] = f.y;
    t[r][c4 + 2] = f.z; t[r][c4 + 3] = f.w;
  }
  __syncthreads();
  #pragma unroll
  for (int it = 0; it < 4; ++it) {
    const int n = it * 16 + (tid >> 4), k4 = (tid & 15) * 4;
    ushort4 uh;
    uh.x = f2bf(t[k4 + 0][n]); uh.y = f2bf(t[k4 + 1][n]);
    uh.z = f2bf(t[k4 + 2][n]); uh.w = f2bf(t[k4 + 3][n]);
    *(ushort4*)&Wh[(size_t)(n0 + n) * D_MODEL + k0 + k4] = uh;
  }
}

// ---------------------------------------------------------------------------
// Fused Q/K/V projections. 128x128 tile, BK=64, 512 threads (8 waves 2x4),
// LDS 64KB -> 2 blocks/CU (m97 structure). grid 768 = 3 x 256.
// which==2 writes per-head-transposed Vt; which==0 pre-scales by 0.125.
// ---------------------------------------------------------------------------
__global__ __launch_bounds__(512, 4) void gemm_qkv(
    const unsigned short* __restrict__ qx, const unsigned short* __restrict__ kx,
    const unsigned short* __restrict__ vx,
    const unsigned short* __restrict__ Wqt, const unsigned short* __restrict__ Wkt,
    const unsigned short* __restrict__ Wvt,
    const float* __restrict__ bq, const float* __restrict__ bk,
    const float* __restrict__ bv,
    unsigned short* __restrict__ Qo, unsigned short* __restrict__ Ko,
    unsigned short* __restrict__ Vto) {
  __shared__ char lds[65536];                 // 2 x (16K A + 16K B)
  const int tid = threadIdx.x;
  const int lane = tid & 63, wid = tid >> 6;
  const int r16 = lane & 15, g = lane >> 4;
  const int bid = blockIdx.x;
  const int orig = (bid & 7) * 96 + (bid >> 3);   // XCD swizzle (768%8==0)
  const int which = orig >> 8;                    // 0:Q 1:K 2:V
  const int sub = orig & 255;
  const int bm = sub >> 3, bn = sub & 7;
  const int row0 = bm * 128, col0 = bn * 128;
  const int wm = wid >> 2, wn = wid & 3;          // 2 x 4 waves

  const unsigned short* A = (which == 0) ? qx : (which == 1) ? kx : vx;
  const unsigned short* W = (which == 0) ? Wqt : (which == 1) ? Wkt : Wvt;
  const float* bias = (which == 0) ? bq : (which == 1) ? bk : bv;

  const unsigned short* Ag = A + (size_t)row0 * D_MODEL;
  const unsigned short* Bg = W + (size_t)col0 * D_MODEL;

  auto stage = [&](int buf, int k0) {
    char* base = lds + buf * 32768;
    #pragma unroll
    for (int c = 0; c < 2; ++c) {             // 128 rows x 64 k each of A,B
      const int idx = c * 512 + tid;
      const int r = idx >> 3, ch = idx & 7;
      const size_t off = (size_t)r * D_MODEL + k0 + ((ch ^ (r & 7)) << 3);
      load16(Ag + off, base + idx * 16);
      load16(Bg + off, base + 16384 + idx * 16);
    }
  };

  stage(0, 0);
  f32x4 acc[4][2] = {};

  for (int s = 0; s < 16; ++s) {
    __syncthreads();
    if (s < 15) stage((s + 1) & 1, (s + 1) * 64);
    const char* base = lds + (s & 1) * 32768;
    #pragma unroll
    for (int kk = 0; kk < 2; ++kk) {
      bf16x8 a[4], b[2];
      #pragma unroll
      for (int mi = 0; mi < 4; ++mi) {
        const int r = wm * 64 + mi * 16 + r16;
        a[mi] = *(const bf16x8*)(base + r * 128 + (((g + kk * 4) ^ (r & 7)) << 4));
      }
      #pragma unroll
      for (int ni = 0; ni < 2; ++ni) {
        const int r = wn * 32 + ni * 16 + r16;
        b[ni] = *(const bf16x8*)(base + 16384 + r * 128 +
                                 (((g + kk * 4) ^ (r & 7)) << 4));
      }
      #pragma unroll
      for (int mi = 0; mi < 4; ++mi)
        #pragma unroll
        for (int ni = 0; ni < 2; ++ni)
          acc[mi][ni] = __builtin_amdgcn_mfma_f32_16x16x32_bf16(
              a[mi], b[ni], acc[mi][ni], 0, 0, 0);
    }
  }

  if (which < 2) {
    unsigned short* C = (which == 0) ? Qo : Ko;
    const float scale = (which == 0) ? 0.125f : 1.0f;
    #pragma unroll
    for (int mi = 0; mi < 4; ++mi)
      #pragma unroll
      for (int ni = 0; ni < 2; ++ni) {
        const int col = col0 + wn * 32 + ni * 16 + r16;
        const float bb = bias[col];
        const int rowb = row0 + wm * 64 + mi * 16 + g * 4;
        #pragma unroll
        for (int j = 0; j < 4; ++j)
          C[(size_t)(rowb + j) * D_MODEL + col] =
              f2bf((acc[mi][ni][j] + bb) * scale);
      }
  } else {
    #pragma unroll
    for (int mi = 0; mi < 4; ++mi)
      #pragma unroll
      for (int ni = 0; ni < 2; ++ni) {
        const int col = col0 + wn * 32 + ni * 16 + r16;
        const int hh = col >> 6, dd = col & 63;
        const float bb = bias[col];
        const int rowb = row0 + wm * 64 + mi * 16 + g * 4;
        const int b_ = rowb >> 11, tt = rowb & 2047;
        ushort4 u;
        u.x = f2bf(acc[mi][ni][0] + bb);
        u.y = f2bf(acc[mi][ni][1] + bb);
        u.z = f2bf(acc[mi][ni][2] + bb);
        u.w = f2bf(acc[mi][ni][3] + bb);
        *(ushort4*)&Vto[((size_t)((b_ * NHEAD + hh) * 64 + dd)) * SEQ + tt] = u;
      }
  }
}

// ---------------------------------------------------------------------------
// Final GEMM: out = (Oh + Ol) @ Wh + bias, fp32 out. 128x64 tile, 2-term
// split precision. (validated round 6)
// ---------------------------------------------------------------------------
__global__ __launch_bounds__(512, 4) void gemm128s(
    const unsigned short* __restrict__ A, const unsigned short* __restrict__ Al,
    const unsigned short* __restrict__ B, const float* __restrict__ bias,
    float* __restrict__ O) {
  __shared__ char lds[81920];
  const int tid = threadIdx.x;
  const int lane = tid & 63, wid = tid >> 6;
  const int r16 = lane & 15, g = lane >> 4;
  const int bid = blockIdx.x;
  const int orig = (bid & 7) * 64 + (bid >> 3);   // XCD swizzle (512%8==0)
  const int bm = orig >> 4, bn = orig & 15;
  const int row0 = bm * 128, col0 = bn * 64;
  const int wm = wid >> 1, wn = wid & 1;

  const unsigned short* Ag  = A  + (size_t)row0 * D_MODEL;
  const unsigned short* Alg = Al + (size_t)row0 * D_MODEL;
  const unsigned short* Bg  = B  + (size_t)col0 * D_MODEL;

  auto stage = [&](int buf, int k0) {
    char* base = lds + buf * 40960;
    #pragma unroll
    for (int c = 0; c < 2; ++c) {
      const int idx = c * 512 + tid;
      const int r = idx >> 3, ch = idx & 7;
      const size_t off = (size_t)r * D_MODEL + k0 + ((ch ^ (r & 7)) << 3);
      load16(Ag + off, base + idx * 16);
      load16(Alg + off, base + 16384 + idx * 16);
    }
    {
      const int r = tid >> 3, ch = tid & 7;
      load16(Bg + (size_t)r * D_MODEL + k0 + ((ch ^ (r & 7)) << 3),
             base + 32768 + tid * 16);
    }
  };

  stage(0, 0);
  f32x4 acc[2][2] = {};

  for (int s = 0; s < 16; ++s) {
    __syncthreads();
    if (s < 15) stage((s + 1) & 1, (s + 1) * 64);
    const char* base = lds + (s & 1) * 40960;
    #pragma unroll
    for (int kk = 0; kk < 2; ++kk) {
      bf16x8 a[2], al[2], b[2];
      #pragma unroll
      for (int mi = 0; mi < 2; ++mi) {
        const int r = wm * 32 + mi * 16 + r16;
        const int off = r * 128 + (((g + kk * 4) ^ (r & 7)) << 4);
        a[mi]  = *(const bf16x8*)(base + off);
        al[mi] = *(const bf16x8*)(base + 16384 + off);
      }
      #pragma unroll
      for (int ni = 0; ni < 2; ++ni) {
        const int r = wn * 32 + ni * 16 + r16;
        b[ni] = *(const bf16x8*)(base + 32768 + r * 128 +
                                 (((g + kk * 4) ^ (r & 7)) << 4));
      }
      #pragma unroll
      for (int mi = 0; mi < 2; ++mi)
        #pragma unroll
        for (int ni = 0; ni < 2; ++ni) {
          acc[mi][ni] = __builtin_amdgcn_mfma_f32_16x16x32_bf16(
              a[mi], b[ni], acc[mi][ni], 0, 0, 0);
          acc[mi][ni] = __builtin_amdgcn_mfma_f32_16x16x32_bf16(
              al[mi], b[ni], acc[mi][ni], 0, 0, 0);
        }
    }
  }

  #pragma unroll
  for (int mi = 0; mi < 2; ++mi)
    #pragma unroll
    for (int ni = 0; ni < 2; ++ni) {
      const int col = col0 + wn * 32 + ni * 16 + r16;
      const float bb = bias[col];
      const int rowb = row0 + wm * 32 + mi * 16 + g * 4;
      #pragma unroll
      for (int j = 0; j < 4; ++j)
        O[(size_t)(rowb + j) * D_MODEL + col] = acc[mi][ni][j] + bb;
    }
}

// ---------------------------------------------------------------------------
// Two-pass MFMA attention, QB=64 (validated round 6, unchanged).
// ---------------------------------------------------------------------------
__global__ __launch_bounds__(512, 4) void attn_2pass(
    const unsigned short* __restrict__ Qb,   // bf16 [4096][1024], pre-scaled /8
    const unsigned short* __restrict__ Kb,   // bf16 [4096][1024]
    const unsigned short* __restrict__ Vt,   // bf16 [32*64][2048]
    const int* __restrict__ mask,            // [2][2048]
    float* __restrict__ attn,                // [32][2048][2048]
    unsigned short* __restrict__ Oh,         // bf16 hi [4096][1024]
    unsigned short* __restrict__ Ol) {       // bf16 lo [4096][1024]
  __shared__ char lds[74752];
  char* const Kbuf = lds;                    // 4 x 8192
  char* const Vbuf = lds + 32768;            // 4 x 8192 (slot0 = Q staging)
  char* const Pt   = lds + 65536;            // 8192: P tile 64x64 bf16
  float* const red = (float*)(lds + 73728);  // [4 wt][64 q]

  const int tid  = threadIdx.x;
  const int lane = tid & 63;
  const int wid  = tid >> 6;
  const int r16  = lane & 15;
  const int g    = lane >> 4;
  const int wq2  = wid >> 2;
  const int wt   = wid & 3;

  const int bid  = blockIdx.x;
  const int orig = (bid & 7) * 128 + (bid >> 3);   // XCD swizzle (1024%8==0)
  const int bh   = orig >> 5;
  const int qblk = orig & 31;
  const int b    = bh >> 4, h = bh & 15;
  const int q0   = qblk * 64;

  const unsigned short* Kg0 = Kb + (size_t)(b * SEQ) * D_MODEL + h * 64;
  const unsigned short* Qg0 = Qb + (size_t)(b * SEQ + q0) * D_MODEL + h * 64;
  const unsigned short* Vg0 = Vt + (size_t)(bh * 64) * SEQ;
  const int* mrow = mask + b * SEQ;

  const int srow = tid >> 3, sch = tid & 7;
  const int ssw  = srow & 7;

  auto stageK = [&](int t) {
    load16((const char*)(Kg0 + (size_t)(t * 64 + srow) * D_MODEL) +
               ((sch ^ ssw) << 4),
           Kbuf + ((t & 3) << 13) + tid * 16);
  };
  auto stageV = [&](int t) {
    load16((const char*)(Vg0 + (size_t)srow * SEQ + t * 64) +
               ((sch ^ ssw) << 4),
           Vbuf + ((t & 3) << 13) + tid * 16);
  };

  // per-lane mask bits for t = i*64 + wt*16 + r16 (consumed before staging)
  const int tb = wt * 16 + r16;
  unsigned mbits = 0;
  #pragma unroll 4
  for (int i = 0; i < 32; ++i)
    mbits |= (mrow[i * 64 + tb] ? 1u : 0u) << i;
  asm volatile("s_waitcnt vmcnt(0)" ::: "memory");  // clean FIFO before staging

  // ---- prologue: Q into Vbuf slot0, K tiles 0..2 -------------------------
  load16((const char*)(Qg0 + (size_t)srow * D_MODEL) + ((sch ^ ssw) << 4),
         Vbuf + tid * 16);
  stageK(0); stageK(1); stageK(2);
  asm volatile("s_waitcnt vmcnt(3)\n\ts_barrier" ::: "memory");  // Q resident

  bf16x8 qa[2][2];
  #pragma unroll
  for (int f = 0; f < 2; ++f) {
    const int row = wq2 * 32 + f * 16 + r16;
    const int sw = (row & 7) << 4;
    qa[f][0] = *(const bf16x8*)(Vbuf + row * 128 + ((g * 16) ^ sw));
    qa[f][1] = *(const bf16x8*)(Vbuf + row * 128 + ((g * 16 + 64) ^ sw));
  }

  const int krow = wt * 16 + r16;
  const int ksw  = (krow & 7) << 4;

  // ---- pass 1: rowsums ---------------------------------------------------
  float rs[2][4] = {};
  for (int i = 0; i < 32; ++i) {
    if (i < 30)
      asm volatile("s_waitcnt vmcnt(2)\n\ts_barrier" ::: "memory");
    else if (i == 30)
      asm volatile("s_waitcnt vmcnt(1)\n\ts_barrier" ::: "memory");
    else
      asm volatile("s_waitcnt vmcnt(0)\n\ts_barrier" ::: "memory");
    if (i + 3 < 32) stageK(i + 3);
    const char* Kt = Kbuf + ((i & 3) << 13);
    const bf16x8 kb0 = *(const bf16x8*)(Kt + krow * 128 + ((g * 16) ^ ksw));
    const bf16x8 kb1 = *(const bf16x8*)(Kt + krow * 128 + ((g * 16 + 64) ^ ksw));
    f32x4 c0 = {0.f, 0.f, 0.f, 0.f}, c1 = {0.f, 0.f, 0.f, 0.f};
    __builtin_amdgcn_s_setprio(1);
    c0 = __builtin_amdgcn_mfma_f32_16x16x32_bf16(qa[0][0], kb0, c0, 0, 0, 0);
    c0 = __builtin_amdgcn_mfma_f32_16x16x32_bf16(qa[0][1], kb1, c0, 0, 0, 0);
    c1 = __builtin_amdgcn_mfma_f32_16x16x32_bf16(qa[1][0], kb0, c1, 0, 0, 0);
    c1 = __builtin_amdgcn_mfma_f32_16x16x32_bf16(qa[1][1], kb1, c1, 0, 0, 0);
    __builtin_amdgcn_s_setprio(0);
    if (!((mbits >> i) & 1u)) {
      rs[0][0] += __expf(c0[0]); rs[0][1] += __expf(c0[1]);
      rs[0][2] += __expf(c0[2]); rs[0][3] += __expf(c0[3]);
      rs[1][0] += __expf(c1[0]); rs[1][1] += __expf(c1[1]);
      rs[1][2] += __expf(c1[2]); rs[1][3] += __expf(c1[3]);
    }
  }

  // ---- rowsum reduction (16-lane groups share a q-frag row set) ----------
  #pragma unroll
  for (int f = 0; f < 2; ++f)
    #pragma unroll
    for (int j = 0; j < 4; ++j) {
      float v = rs[f][j];
      v += __shfl_xor(v, 1); v += __shfl_xor(v, 2);
      v += __shfl_xor(v, 4); v += __shfl_xor(v, 8);
      rs[f][j] = v;
    }
  if (r16 == 0) {
    #pragma unroll
    for (int f = 0; f < 2; ++f)
      #pragma unroll
      for (int j = 0; j < 4; ++j)
        red[wt * 64 + wq2 * 32 + f * 16 + g * 4 + j] = rs[f][j];
  }
  __syncthreads();

  float inv_[2][4];
  #pragma unroll
  for (int f = 0; f < 2; ++f)
    #pragma unroll
    for (int j = 0; j < 4; ++j) {
      const int row = wq2 * 32 + f * 16 + g * 4 + j;
      inv_[f][j] = 1.f / (red[0 * 64 + row] + red[1 * 64 + row] +
                          red[2 * 64 + row] + red[3 * 64 + row]);
    }

  // ---- pass 2 prologue ---------------------------------------------------
  stageK(0); stageV(0); stageK(1); stageV(1); stageK(2); stageV(2);

  f32x4 o0 = {0.f, 0.f, 0.f, 0.f}, o1 = {0.f, 0.f, 0.f, 0.f};
  // readback mapping: thread -> q row tid>>3, 8 cols at (tid&7)*8
  const int rbq = tid >> 3, rbc8 = (tid & 7) * 8;
  const int rboff = (rbq * 128 + rbc8 * 2) ^ ((rbq & 7) << 4);
  float* const aT = attn + ((size_t)bh * SEQ + q0 + rbq) * SEQ + rbc8;

  for (int i = 0; i < 32; ++i) {
    // FIFO (2 loads + 2 stores/iter, 3-deep prefetch): 4,6,8,10..10,8,6
    if (i >= 3 && i <= 29)
      asm volatile("s_waitcnt vmcnt(10)\n\ts_barrier" ::: "memory");
    else if (i == 2 || i == 30)
      asm volatile("s_waitcnt vmcnt(8)\n\ts_barrier" ::: "memory");
    else if (i == 1 || i == 31)
      asm volatile("s_waitcnt vmcnt(6)\n\ts_barrier" ::: "memory");
    else
      asm volatile("s_waitcnt vmcnt(4)\n\ts_barrier" ::: "memory");
    if (i + 3 < 32) { stageK(i + 3); stageV(i + 3); }

    const char* Kt = Kbuf + ((i & 3) << 13);
    const bf16x8 kb0 = *(const bf16x8*)(Kt + krow * 128 + ((g * 16) ^ ksw));
    const bf16x8 kb1 = *(const bf16x8*)(Kt + krow * 128 + ((g * 16 + 64) ^ ksw));
    f32x4 c0 = {0.f, 0.f, 0.f, 0.f}, c1 = {0.f, 0.f, 0.f, 0.f};
    __builtin_amdgcn_s_setprio(1);
    c0 = __builtin_amdgcn_mfma_f32_16x16x32_bf16(qa[0][0], kb0, c0, 0, 0, 0);
    c0 = __builtin_amdgcn_mfma_f32_16x16x32_bf16(qa[0][1], kb1, c0, 0, 0, 0);
    c1 = __builtin_amdgcn_mfma_f32_16x16x32_bf16(qa[1][0], kb0, c1, 0, 0, 0);
    c1 = __builtin_amdgcn_mfma_f32_16x16x32_bf16(qa[1][1], kb1, c1, 0, 0, 0);
    __builtin_amdgcn_s_setprio(0);

    const unsigned mk = (mbits >> i) & 1u;
    float p[2][4];
    p[0][0] = mk ? 0.f : __expf(c0[0]) * inv_[0][0];
    p[0][1] = mk ? 0.f : __expf(c0[1]) * inv_[0][1];
    p[0][2] = mk ? 0.f : __expf(c0[2]) * inv_[0][2];
    p[0][3] = mk ? 0.f : __expf(c0[3]) * inv_[0][3];
    p[1][0] = mk ? 0.f : __expf(c1[0]) * inv_[1][0];
    p[1][1] = mk ? 0.f : __expf(c1[1]) * inv_[1][1];
    p[1][2] = mk ? 0.f : __expf(c1[2]) * inv_[1][2];
    p[1][3] = mk ? 0.f : __expf(c1[3]) * inv_[1][3];

    #pragma unroll
    for (int f = 0; f < 2; ++f)
      #pragma unroll
      for (int j = 0; j < 4; ++j) {
        const int row = wq2 * 32 + f * 16 + g * 4 + j;
        *(unsigned short*)(Pt + ((row * 128 + tb * 2) ^ ((row & 7) << 4))) =
            f2bf(p[f][j]);
      }

    asm volatile("s_waitcnt lgkmcnt(0)\n\ts_barrier" ::: "memory");

    const char* Vtl = Vbuf + ((i & 3) << 13);
    const bf16x8 vb0 = *(const bf16x8*)(Vtl + krow * 128 + ((g * 16) ^ ksw));
    const bf16x8 vb1 = *(const bf16x8*)(Vtl + krow * 128 + ((g * 16 + 64) ^ ksw));
    {
      const int pr0 = wq2 * 32 + r16;
      const int psw0 = (pr0 & 7) << 4;
      const bf16x8 pa0 = *(const bf16x8*)(Pt + pr0 * 128 + ((g * 16) ^ psw0));
      const bf16x8 pa1 = *(const bf16x8*)(Pt + pr0 * 128 + ((g * 16 + 64) ^ psw0));
      const int pr1 = pr0 + 16;
      const int psw1 = (pr1 & 7) << 4;
      const bf16x8 pb0 = *(const bf16x8*)(Pt + pr1 * 128 + ((g * 16) ^ psw1));
      const bf16x8 pb1 = *(const bf16x8*)(Pt + pr1 * 128 + ((g * 16 + 64) ^ psw1));
      __builtin_amdgcn_s_setprio(1);
      o0 = __builtin_amdgcn_mfma_f32_16x16x32_bf16(pa0, vb0, o0, 0, 0, 0);
      o0 = __builtin_amdgcn_mfma_f32_16x16x32_bf16(pa1, vb1, o0, 0, 0, 0);
      o1 = __builtin_amdgcn_mfma_f32_16x16x32_bf16(pb0, vb0, o1, 0, 0, 0);
      o1 = __builtin_amdgcn_mfma_f32_16x16x32_bf16(pb1, vb1, o1, 0, 0, 0);
      __builtin_amdgcn_s_setprio(0);
    }

    // coalesced attn write: u16x8 LDS readback -> 2 float4 stores
    {
      const u16x8 pv = *(const u16x8*)(Pt + rboff);
      float4 oA, oB;
      oA.x = bf2f(pv[0]); oA.y = bf2f(pv[1]);
      oA.z = bf2f(pv[2]); oA.w = bf2f(pv[3]);
      oB.x = bf2f(pv[4]); oB.y = bf2f(pv[5]);
      oB.z = bf2f(pv[6]); oB.w = bf2f(pv[7]);
      *(float4*)(aT + (size_t)i * 64) = oA;
      *(float4*)(aT + (size_t)i * 64 + 4) = oB;
    }
  }

  // ---- O epilogue (already normalized), bf16 hi/lo -----------------------
  #pragma unroll
  for (int f = 0; f < 2; ++f)
    #pragma unroll
    for (int j = 0; j < 4; ++j) {
      const int row = q0 + wq2 * 32 + f * 16 + g * 4 + j;
      const size_t idx = (size_t)(b * SEQ + row) * D_MODEL + h * 64 + wt * 16 + r16;
      const float o = f ? o1[j] : o0[j];
      const unsigned short ohv = f2bf(o);
      Oh[idx] = ohv;
      Ol[idx] = f2bf(o - bf2f(ohv));
    }
}

// ---------------------------------------------------------------------------
extern "C" void kernel_launch(void* const* d_in, const int* in_sizes, int n_in,
                              void* d_out, int out_size, void* d_ws, size_t ws_size,
                              hipStream_t stream) {
  const float* v    = (const float*)d_in[0];
  const float* k    = (const float*)d_in[1];
  const float* q    = (const float*)d_in[2];
  const int*   mask = (const int*)  d_in[3];
  const float* Wq   = (const float*)d_in[4];
  const float* bq   = (const float*)d_in[5];
  const float* Wk   = (const float*)d_in[6];
  const float* bk   = (const float*)d_in[7];
  const float* Wv   = (const float*)d_in[8];
  const float* bv   = (const float*)d_in[9];
  const float* Wo   = (const float*)d_in[10];
  const float* bo   = (const float*)d_in[11];

  const size_t NTOK = (size_t)2 * SEQ;            // 4096 tokens
  const size_t TOKF = NTOK * D_MODEL;             // 4,194,304 elements
  const size_t WSZ  = (size_t)D_MODEL * D_MODEL;  // 1,048,576
  float* out  = (float*)d_out;
  float* attn = out + TOKF;

  unsigned short* qx   = (unsigned short*)d_ws;   // bf16 inputs
  unsigned short* kx   = qx + TOKF;
  unsigned short* vx   = kx + TOKF;
  unsigned short* Qbf  = vx + TOKF;               // projections
  unsigned short* Kbf  = Qbf + TOKF;
  unsigned short* Vtb  = Kbf + TOKF;
  unsigned short* Ohb  = Vtb + TOKF;              // attn O hi/lo
  unsigned short* Olb  = Ohb + TOKF;
  unsigned short* Wqt  = Olb + TOKF;              // transposed bf16 weights
  unsigned short* Wkt  = Wqt + WSZ;
  unsigned short* Wvt  = Wkt + WSZ;
  unsigned short* Woth = Wvt + WSZ;

  const int cvtg = (int)(TOKF / 4 / 256);         // 4096 blocks
  cvt3_bf16<<<dim3(cvtg, 3), 256, 0, stream>>>(
      (const float4*)q, (const float4*)k, (const float4*)v,
      (ushort4*)qx, (ushort4*)kx, (ushort4*)vx);
  wt_cvt4<<<dim3(16, 16, 4), 256, 0, stream>>>(Wq, Wk, Wv, Wo,
                                               Wqt, Wkt, Wvt, Woth);

  gemm_qkv<<<768, 512, 0, stream>>>(qx, kx, vx, Wqt, Wkt, Wvt,
                                    bq, bk, bv, Qbf, Kbf, Vtb);

  attn_2pass<<<1024, 512, 0, stream>>>(Qbf, Kbf, Vtb, mask, attn, Ohb, Olb);

  gemm128s<<<512, 512, 0, stream>>>(Ohb, Olb, Woth, bo, out);
}